// Round 1
// baseline (18182.478 us; speedup 1.0000x reference)
//
#include <hip/hip_runtime.h>

// MessagePackBlock: E=131072 edges, per-edge small-matvec pipeline, fp32.
// Round 1: correctness-first fused kernel. 16 edges/block, 256 threads.
// Intermediates in LDS (63.5 KiB, phase-reused); weights read from global (L2-hot).

constexpr int T = 16;
constexpr float BETA  = 1.6791767f;
constexpr float RS128 = 0.088388347648318447f;  // 1/sqrt(128)
constexpr float RS64  = 0.125f;                 // 1/sqrt(64)
constexpr float RS32  = 0.176776695296636881f;  // 1/sqrt(32)
constexpr float RSQ3  = 0.577350269189625842f;  // 1/sqrt(3)

struct Ptrs {
  const float *src, *dst, *ef, *env, *scal;
  const float *Wn_ss, *Wn_vv, *Wn_sv, *Wn_vs;
  const float *We_ss, *We_vv, *We_sv, *We_vs;
  const float *Wns_s, *Wns_v, *Wes_s, *Wes_v;
  const float *Wno_s, *Wno_v, *Weo_s, *Weo_v;
  const float *Wnm1, *Wnm2, *Wnm3, *Wem1, *Wem2, *Wem3;
  float *out;
};

__device__ __forceinline__ float silu_beta(float z) {
  return BETA * z / (1.0f + __expf(-z));
}

__global__ __launch_bounds__(256) void mp_kernel(Ptrs P) {
  const int tid = threadIdx.x;
  const int e0  = blockIdx.x * T;

  __shared__ float h1[T][64];    // MLP hidden 1; reused as node "dot" (T x 64)
  __shared__ float h2[T][64];    // MLP hidden 2; reused as edge "dot" (T x 32)
  __shared__ float wn[T][192];   // MLP weights output (node)
  __shared__ float we[T][192];   // MLP weights output (edge)
  __shared__ float ms[T][128];   // tp scalar out (node, then edge)
  __shared__ float mv[T][192];   // tp vector out [w*3+i] (node, then edge)
  __shared__ float ns[T][64];    // scale_linear scalar out (node, then edge)
  __shared__ float nv[T][96];    // scale_linear vector out [w*3+i]

  // ---------------- MLPs: w_n and w_e ----------------
  for (int which = 0; which < 2; ++which) {
    const float* W1 = which ? P.Wem1 : P.Wnm1;
    const float* W2 = which ? P.Wem2 : P.Wnm2;
    const float* W3 = which ? P.Wem3 : P.Wnm3;
    float (*wout)[192] = which ? we : wn;

    for (int j = 0; j < 4; ++j) {                 // h1 = beta*silu(scal@W1/8)
      int idx = tid + j * 256; int e = idx >> 6, n = idx & 63;
      const float* x = P.scal + (size_t)(e0 + e) * 64;
      float acc = 0.f;
      for (int k = 0; k < 64; ++k) acc += x[k] * W1[k * 64 + n];
      h1[e][n] = silu_beta(acc * 0.125f);
    }
    __syncthreads();
    for (int j = 0; j < 4; ++j) {                 // h2 = beta*silu(h1@W2/8)
      int idx = tid + j * 256; int e = idx >> 6, n = idx & 63;
      float acc = 0.f;
      for (int k = 0; k < 64; ++k) acc += h1[e][k] * W2[k * 64 + n];
      h2[e][n] = silu_beta(acc * 0.125f);
    }
    __syncthreads();
    for (int j = 0; j < 12; ++j) {                // w = h2@W3/8  (T x 192)
      int idx = tid + j * 256; int e = idx / 192, n = idx % 192;
      float acc = 0.f;
      for (int k = 0; k < 64; ++k) acc += h2[e][k] * W3[k * 192 + n];
      wout[e][n] = acc * 0.125f;
    }
    __syncthreads();
  }

  // ---------------- node tensor product ----------------
  // dot[e][u] = xv[u]·yv / sqrt3  into h1
  for (int j = 0; j < 4; ++j) {
    int idx = tid + j * 256; int e = idx >> 6, u = idx & 63;
    const float* base = (u < 32) ? P.src : P.dst;
    const float* v3 = base + (size_t)(e0 + e) * 160 + 64 + (u & 31) * 3;
    const float* yv = P.env + (size_t)(e0 + e) * 4 + 1;
    h1[e][u] = (v3[0] * yv[0] + v3[1] * yv[1] + v3[2] * yv[2]) * RSQ3;
  }
  __syncthreads();
  // m_s = [ys*(xs@Wn_ss)/sqrt128 ; (dot@Wn_vv)/8]
  for (int j = 0; j < 8; ++j) {
    int idx = tid + j * 256; int e = idx >> 7, w = idx & 127;
    float acc = 0.f;
    if (w < 64) {
      const float* s_ = P.src + (size_t)(e0 + e) * 160;
      const float* d_ = P.dst + (size_t)(e0 + e) * 160;
      for (int u = 0; u < 64; ++u) acc += s_[u] * P.Wn_ss[u * 64 + w];
      for (int u = 0; u < 64; ++u) acc += d_[u] * P.Wn_ss[(u + 64) * 64 + w];
      ms[e][w] = acc * P.env[(size_t)(e0 + e) * 4] * RS128;
    } else {
      int w2 = w - 64;
      for (int u = 0; u < 64; ++u) acc += h1[e][u] * P.Wn_vv[u * 64 + w2];
      ms[e][w] = acc * RS64;
    }
  }
  // m_v[w][i]: w<32: (xs@Wn_sv)[w]*yv[i]/sqrt128 ; w>=32: ys*(xv_i@Wn_vs)[w-32]/8
  for (int j = 0; j < 12; ++j) {
    int idx = tid + j * 256; int e = idx / 192, r = idx % 192, w = r / 3, i = r % 3;
    const float* envp = P.env + (size_t)(e0 + e) * 4;
    float acc = 0.f;
    if (w < 32) {
      const float* s_ = P.src + (size_t)(e0 + e) * 160;
      const float* d_ = P.dst + (size_t)(e0 + e) * 160;
      for (int u = 0; u < 64; ++u) acc += s_[u] * P.Wn_sv[u * 32 + w];
      for (int u = 0; u < 64; ++u) acc += d_[u] * P.Wn_sv[(u + 64) * 32 + w];
      mv[e][r] = acc * envp[1 + i] * RS128;
    } else {
      int wb = w - 32;
      const float* sv = P.src + (size_t)(e0 + e) * 160 + 64;
      const float* dv = P.dst + (size_t)(e0 + e) * 160 + 64;
      for (int u = 0; u < 32; ++u) acc += sv[u * 3 + i] * P.Wn_vs[u * 32 + wb];
      for (int u = 0; u < 32; ++u) acc += dv[u * 3 + i] * P.Wn_vs[(u + 32) * 32 + wb];
      mv[e][r] = acc * envp[0] * RS64;
    }
  }
  __syncthreads();

  // ---------------- node scale_linear ----------------
  for (int j = 0; j < 4; ++j) {
    int idx = tid + j * 256; int e = idx >> 6, n = idx & 63;
    float acc = 0.f;
    for (int u = 0; u < 128; ++u) acc += ms[e][u] * wn[e][u] * P.Wns_s[u * 64 + n];
    ns[e][n] = acc * RS128;
  }
  for (int j = 0; j < 6; ++j) {
    int idx = tid + j * 256; int e = idx / 96, r = idx % 96, w = r / 3, i = r % 3;
    float acc = 0.f;
    for (int u = 0; u < 64; ++u) acc += mv[e][u * 3 + i] * wn[e][128 + u] * P.Wns_v[u * 32 + w];
    nv[e][r] = acc * RS64;
  }
  __syncthreads();

  // ---------------- node output linear (to registers) + edge dot ----------------
  float ons[4], onv[6];
  for (int j = 0; j < 4; ++j) {
    int idx = tid + j * 256; int e = idx >> 6, n = idx & 63;
    float acc = 0.f;
    for (int u = 0; u < 64; ++u) acc += ns[e][u] * P.Wno_s[u * 64 + n];
    ons[j] = acc * RS64;
  }
  for (int j = 0; j < 6; ++j) {
    int idx = tid + j * 256; int e = idx / 96, r = idx % 96, w = r / 3, i = r % 3;
    float acc = 0.f;
    for (int u = 0; u < 32; ++u) acc += nv[e][u * 3 + i] * P.Wno_v[u * 32 + w];
    onv[j] = acc * RS32;
  }
  // edge dot into h2 (T x 32)
  for (int j = 0; j < 2; ++j) {
    int idx = tid + j * 256; int e = idx >> 5, u = idx & 31;
    const float* v3 = P.ef + (size_t)(e0 + e) * 160 + 64 + u * 3;
    const float* yv = P.env + (size_t)(e0 + e) * 4 + 1;
    h2[e][u] = (v3[0] * yv[0] + v3[1] * yv[1] + v3[2] * yv[2]) * RSQ3;
  }
  __syncthreads();

  // ---------------- edge tensor product (m1s=64, m1v=32) ----------------
  for (int j = 0; j < 8; ++j) {
    int idx = tid + j * 256; int e = idx >> 7, w = idx & 127;
    float acc = 0.f;
    if (w < 64) {
      const float* es_ = P.ef + (size_t)(e0 + e) * 160;
      for (int u = 0; u < 64; ++u) acc += es_[u] * P.We_ss[u * 64 + w];
      ms[e][w] = acc * P.env[(size_t)(e0 + e) * 4] * RS64;
    } else {
      int w2 = w - 64;
      for (int u = 0; u < 32; ++u) acc += h2[e][u] * P.We_vv[u * 64 + w2];
      ms[e][w] = acc * RS32;
    }
  }
  for (int j = 0; j < 12; ++j) {
    int idx = tid + j * 256; int e = idx / 192, r = idx % 192, w = r / 3, i = r % 3;
    const float* envp = P.env + (size_t)(e0 + e) * 4;
    float acc = 0.f;
    if (w < 32) {
      const float* es_ = P.ef + (size_t)(e0 + e) * 160;
      for (int u = 0; u < 64; ++u) acc += es_[u] * P.We_sv[u * 32 + w];
      mv[e][r] = acc * envp[1 + i] * RS64;
    } else {
      int wb = w - 32;
      const float* ev_ = P.ef + (size_t)(e0 + e) * 160 + 64;
      for (int u = 0; u < 32; ++u) acc += ev_[u * 3 + i] * P.We_vs[u * 32 + wb];
      mv[e][r] = acc * envp[0] * RS32;
    }
  }
  __syncthreads();

  // ---------------- edge scale_linear ----------------
  for (int j = 0; j < 4; ++j) {
    int idx = tid + j * 256; int e = idx >> 6, n = idx & 63;
    float acc = 0.f;
    for (int u = 0; u < 128; ++u) acc += ms[e][u] * we[e][u] * P.Wes_s[u * 64 + n];
    ns[e][n] = acc * RS128;
  }
  for (int j = 0; j < 6; ++j) {
    int idx = tid + j * 256; int e = idx / 96, r = idx % 96, w = r / 3, i = r % 3;
    float acc = 0.f;
    for (int u = 0; u < 64; ++u) acc += mv[e][u * 3 + i] * we[e][128 + u] * P.Wes_v[u * 32 + w];
    nv[e][r] = acc * RS64;
  }
  __syncthreads();

  // ---------------- edge output linear + final store ----------------
  for (int j = 0; j < 4; ++j) {
    int idx = tid + j * 256; int e = idx >> 6, n = idx & 63;
    float acc = 0.f;
    for (int u = 0; u < 64; ++u) acc += ns[e][u] * P.Weo_s[u * 64 + n];
    P.out[(size_t)(e0 + e) * 160 + n] = ons[j] + acc * RS64;
  }
  for (int j = 0; j < 6; ++j) {
    int idx = tid + j * 256; int e = idx / 96, r = idx % 96, w = r / 3, i = r % 3;
    float acc = 0.f;
    for (int u = 0; u < 32; ++u) acc += nv[e][u * 3 + i] * P.Weo_v[u * 32 + w];
    P.out[(size_t)(e0 + e) * 160 + 64 + r] = onv[j] + acc * RS32;
  }
}

extern "C" void kernel_launch(void* const* d_in, const int* in_sizes, int n_in,
                              void* d_out, int out_size, void* d_ws, size_t ws_size,
                              hipStream_t stream) {
  Ptrs P;
  P.src   = (const float*)d_in[0];
  P.dst   = (const float*)d_in[1];
  P.ef    = (const float*)d_in[2];
  P.env   = (const float*)d_in[3];
  P.scal  = (const float*)d_in[4];
  P.Wn_ss = (const float*)d_in[5];
  P.Wn_vv = (const float*)d_in[6];
  P.Wn_sv = (const float*)d_in[7];
  P.Wn_vs = (const float*)d_in[8];
  P.We_ss = (const float*)d_in[9];
  P.We_vv = (const float*)d_in[10];
  P.We_sv = (const float*)d_in[11];
  P.We_vs = (const float*)d_in[12];
  P.Wns_s = (const float*)d_in[13];
  P.Wns_v = (const float*)d_in[14];
  P.Wes_s = (const float*)d_in[15];
  P.Wes_v = (const float*)d_in[16];
  P.Wno_s = (const float*)d_in[17];
  P.Wno_v = (const float*)d_in[18];
  P.Weo_s = (const float*)d_in[19];
  P.Weo_v = (const float*)d_in[20];
  P.Wnm1  = (const float*)d_in[21];
  P.Wnm2  = (const float*)d_in[22];
  P.Wnm3  = (const float*)d_in[23];
  P.Wem1  = (const float*)d_in[24];
  P.Wem2  = (const float*)d_in[25];
  P.Wem3  = (const float*)d_in[26];
  P.out   = (float*)d_out;

  const int E = in_sizes[0] / 160;  // 131072
  mp_kernel<<<dim3(E / T), dim3(256), 0, stream>>>(P);
}

// Round 2
// 767.384 us; speedup vs baseline: 23.6941x; 23.6941x over previous
//
#include <hip/hip_runtime.h>

// R2: fused MFMA (bf16) pipeline. 32 edges/block, 256 threads (4 waves).
// All GEMMs computed as D' = W^T * x^T with mfma_f32_16x16x32_bf16.
// Intermediates: bf16 LDS edge-major [m][k] (padded rows). Weights: staged
// transposed [n][k] per phase into shared W buffer. Accumulation f32.

typedef short  bf16x8 __attribute__((ext_vector_type(8)));
typedef float  f32x4  __attribute__((ext_vector_type(4)));

constexpr float BETA  = 1.6791767f;
constexpr float RS128 = 0.088388347648318447f;
constexpr float RS64  = 0.125f;
constexpr float RS32  = 0.176776695296636881f;
constexpr float RSQ3  = 0.577350269189625842f;

struct Ptrs {
  const float *src, *dst, *ef, *env, *scal;
  const float *Wn_ss, *Wn_vv, *Wn_sv, *Wn_vs;
  const float *We_ss, *We_vv, *We_sv, *We_vs;
  const float *Wns_s, *Wns_v, *Wes_s, *Wes_v;
  const float *Wno_s, *Wno_v, *Weo_s, *Weo_v;
  const float *Wnm1, *Wnm2, *Wnm3, *Wem1, *Wem2, *Wem3;
  float *out;
};

__device__ __forceinline__ ushort f2b(float x) {
  union { float f; unsigned u; } v; v.f = x;
  unsigned r = v.u + 0x7fffu + ((v.u >> 16) & 1u);
  return (ushort)(r >> 16);
}
__device__ __forceinline__ float b2f(unsigned h) {
  union { unsigned u; float f; } v; v.u = h << 16; return v.f;
}
__device__ __forceinline__ void st4(ushort* p, float a0, float a1, float a2, float a3) {
  uint2 v;
  v.x = (unsigned)f2b(a0) | ((unsigned)f2b(a1) << 16);
  v.y = (unsigned)f2b(a2) | ((unsigned)f2b(a3) << 16);
  *(uint2*)p = v;
}

// one 16x16 output tile, K = KS*32: A = Wt rows n0..n0+15, B = X rows (edges)
template<int KS>
__device__ __forceinline__ f32x4 gemm_one(const ushort* __restrict__ Wt, int wst,
                                          const ushort* __restrict__ X, int xst,
                                          int n0, int c, int gofs, int mrow, f32x4 acc) {
#pragma unroll
  for (int ks = 0; ks < KS; ++ks) {
    bf16x8 a = *(const bf16x8*)(Wt + (n0 + c) * wst + ks * 32 + gofs);
    bf16x8 b = *(const bf16x8*)(X  + mrow     * xst + ks * 32 + gofs);
    acc = __builtin_amdgcn_mfma_f32_16x16x32_bf16(a, b, acc, 0, 0, 0);
  }
  return acc;
}

template<int N>
__device__ __forceinline__ void stage_wT(const float* __restrict__ src, int K,
                                         ushort* dst, int stride, int tid) {
  for (int idx = tid; idx < K * N; idx += 256) {
    int k = idx / N, n = idx - k * N;
    dst[n * stride + k] = f2b(src[idx]);
  }
}

__global__ __launch_bounds__(256, 1) void mp_kernel(Ptrs P) {
  const int tid  = threadIdx.x;
  const int e0   = blockIdx.x * 32;
  const int lane = tid & 63, wid = tid >> 6;
  const int mt   = wid & 1,  nh  = wid >> 1;
  const int c    = lane & 15, g  = lane >> 4;
  const int gofs = g * 8;
  const int mrow = mt * 16 + c;          // local edge index this lane's D column

  __shared__ ushort s_scal[32 * 72];
  __shared__ float  s_env [32 * 4];
  __shared__ ushort s_xs  [32 * 136];    // node xs / edge es (stride 136)
  __shared__ ushort s_xv  [3 * 32 * 72]; // node xv_i / edge ev_i
  __shared__ ushort s_dot [32 * 72];     // node dot / edge dot
  __shared__ ushort s_h   [2 * 32 * 72]; // MLP hidden ping-pong
  __shared__ ushort s_w   [32 * 200];    // MLP output w (192 + pad)
  __shared__ ushort s_msp [32 * 136];    // (m_s * w) tile
  __shared__ ushort s_mvp [3 * 32 * 72]; // (m_v_i * w) tiles
  __shared__ ushort s_ns  [32 * 72];
  __shared__ ushort s_nv  [3 * 32 * 40];
  __shared__ ushort s_W   [13824];       // staged transposed weights (reused)

  // ---------------- S0: stage env, scal, node x-tiles, Wnm1 ----------------
  if (tid < 128) s_env[tid] = P.env[(size_t)e0 * 4 + tid];
  for (int idx = tid; idx < 32 * 16; idx += 256) {            // scal [32][64]
    int m = idx >> 4, q = idx & 15;
    float4 v = *(const float4*)(P.scal + (size_t)(e0 + m) * 64 + q * 4);
    st4(&s_scal[m * 72 + q * 4], v.x, v.y, v.z, v.w);
  }
  for (int idx = tid; idx < 32 * 32; idx += 256) {            // xs = [ss|ds]
    int m = idx >> 5, q = idx & 31;
    const float* basep = (q < 16) ? P.src : P.dst;
    float4 v = *(const float4*)(basep + (size_t)(e0 + m) * 160 + (q & 15) * 4);
    st4(&s_xs[m * 136 + q * 4], v.x, v.y, v.z, v.w);
  }
  for (int idx = tid; idx < 32 * 96; idx += 256) {            // sv part of xv
    int m = idx / 96, j = idx - m * 96, u = j / 3, i = j - u * 3;
    s_xv[i * 2304 + m * 72 + u] = f2b(P.src[(size_t)(e0 + m) * 160 + 64 + j]);
  }
  for (int idx = tid; idx < 32 * 96; idx += 256) {            // dv part of xv
    int m = idx / 96, j = idx - m * 96, u = j / 3, i = j - u * 3;
    s_xv[i * 2304 + m * 72 + 32 + u] = f2b(P.dst[(size_t)(e0 + m) * 160 + 64 + j]);
  }
  for (int idx = tid; idx < 32 * 64; idx += 256) {            // dot_n
    int m = idx >> 6, u = idx & 63;
    const float* basep = (u < 32) ? P.src : P.dst;
    const float* v3 = basep + (size_t)(e0 + m) * 160 + 64 + (u & 31) * 3;
    const float* yv = P.env + (size_t)(e0 + m) * 4 + 1;
    s_dot[m * 72 + u] = f2b((v3[0]*yv[0] + v3[1]*yv[1] + v3[2]*yv[2]) * RSQ3);
  }
  stage_wT<64>(P.Wnm1, 64, s_W, 72, tid);
  __syncthreads();

  // ================= node + edge MLP/TP/SL/OUT =================
  f32x4 oacc_s[2]; f32x4 oacc_v[3];
  for (int t = 0; t < 2; ++t) oacc_s[t] = (f32x4){0,0,0,0};
  for (int i = 0; i < 3; ++i) oacc_v[i] = (f32x4){0,0,0,0};

  const float ysm  = s_env[mrow * 4 + 0];
  const float yvm0 = s_env[mrow * 4 + 1];
  const float yvm1 = s_env[mrow * 4 + 2];
  const float yvm2 = s_env[mrow * 4 + 3];

  for (int path = 0; path < 2; ++path) {   // 0 = node, 1 = edge
    const bool ed = (path == 1);

    if (ed) {
      // ---- stage edge x-tiles (reuse node regions) + Wem1 ----
      for (int idx = tid; idx < 32 * 16; idx += 256) {          // es [32][64]
        int m = idx >> 4, q = idx & 15;
        float4 v = *(const float4*)(P.ef + (size_t)(e0 + m) * 160 + q * 4);
        st4(&s_xs[m * 136 + q * 4], v.x, v.y, v.z, v.w);
      }
      for (int idx = tid; idx < 32 * 96; idx += 256) {          // ev_i
        int m = idx / 96, j = idx - m * 96, u = j / 3, i = j - u * 3;
        s_xv[i * 2304 + m * 72 + u] = f2b(P.ef[(size_t)(e0 + m) * 160 + 64 + j]);
      }
      for (int idx = tid; idx < 32 * 32; idx += 256) {          // dot_e
        int m = idx >> 5, u = idx & 31;
        const float* v3 = P.ef + (size_t)(e0 + m) * 160 + 64 + u * 3;
        const float* yv = P.env + (size_t)(e0 + m) * 4 + 1;
        s_dot[m * 72 + u] = f2b((v3[0]*yv[0] + v3[1]*yv[1] + v3[2]*yv[2]) * RSQ3);
      }
      stage_wT<64>(P.Wem1, 64, s_W, 72, tid);
      __syncthreads();
    }

    // ---- MLP layer 1 ----
    for (int nt = 0; nt < 2; ++nt) {
      int n0 = nh * 32 + nt * 16;
      f32x4 acc = gemm_one<2>(s_W, 72, s_scal, 72, n0, c, gofs, mrow, (f32x4){0,0,0,0});
      float o[4];
#pragma unroll
      for (int r = 0; r < 4; ++r) { float z = acc[r]*0.125f; o[r] = BETA*z/(1.f+__expf(-z)); }
      st4(&s_h[mrow * 72 + n0 + g * 4], o[0], o[1], o[2], o[3]);
    }
    __syncthreads();
    stage_wT<64>(ed ? P.Wem2 : P.Wnm2, 64, s_W, 72, tid);
    __syncthreads();
    // ---- MLP layer 2 ----
    for (int nt = 0; nt < 2; ++nt) {
      int n0 = nh * 32 + nt * 16;
      f32x4 acc = gemm_one<2>(s_W, 72, s_h, 72, n0, c, gofs, mrow, (f32x4){0,0,0,0});
      float o[4];
#pragma unroll
      for (int r = 0; r < 4; ++r) { float z = acc[r]*0.125f; o[r] = BETA*z/(1.f+__expf(-z)); }
      st4(&s_h[2304 + mrow * 72 + n0 + g * 4], o[0], o[1], o[2], o[3]);
    }
    __syncthreads();
    stage_wT<192>(ed ? P.Wem3 : P.Wnm3, 64, s_W, 72, tid);
    __syncthreads();
    // ---- MLP layer 3: w ----
    for (int nt = 0; nt < 6; ++nt) {
      int n0 = nh * 96 + nt * 16;
      f32x4 acc = gemm_one<2>(s_W, 72, s_h + 2304, 72, n0, c, gofs, mrow, (f32x4){0,0,0,0});
      st4(&s_w[mrow * 200 + n0 + g * 4], acc[0]*0.125f, acc[1]*0.125f, acc[2]*0.125f, acc[3]*0.125f);
    }
    __syncthreads();

    // ---- TP group 1: ss + sv ----
    const float SA = ed ? RS64 : RS128;     // scale for s_a / v_a
    if (!ed) { stage_wT<64>(P.Wn_ss, 128, s_W, 136, tid); stage_wT<32>(P.Wn_sv, 128, s_W + 8704, 136, tid); }
    else     { stage_wT<64>(P.We_ss,  64, s_W,  72, tid); stage_wT<32>(P.We_sv,  64, s_W + 4608,  72, tid); }
    __syncthreads();
    for (int nt = 0; nt < 2; ++nt) {        // s_a -> msp[:, :64]
      int n0 = nh * 32 + nt * 16;
      f32x4 acc = ed ? gemm_one<2>(s_W, 72, s_xs, 136, n0, c, gofs, mrow, (f32x4){0,0,0,0})
                     : gemm_one<4>(s_W, 136, s_xs, 136, n0, c, gofs, mrow, (f32x4){0,0,0,0});
      uint2 wp = *(const uint2*)&s_w[mrow * 200 + n0 + g * 4];
      float w0 = b2f(wp.x & 0xffff), w1 = b2f(wp.x >> 16), w2 = b2f(wp.y & 0xffff), w3 = b2f(wp.y >> 16);
      st4(&s_msp[mrow * 136 + n0 + g * 4],
          acc[0]*ysm*SA*w0, acc[1]*ysm*SA*w1, acc[2]*ysm*SA*w2, acc[3]*ysm*SA*w3);
    }
    {                                       // v_a -> mvp[i][:, :32]
      int n0 = nh * 16;
      const ushort* Wt = s_W + (ed ? 4608 : 8704);
      f32x4 acc = ed ? gemm_one<2>(Wt, 72, s_xs, 136, n0, c, gofs, mrow, (f32x4){0,0,0,0})
                     : gemm_one<4>(Wt, 136, s_xs, 136, n0, c, gofs, mrow, (f32x4){0,0,0,0});
      uint2 wp = *(const uint2*)&s_w[mrow * 200 + 128 + n0 + g * 4];
      float w0 = b2f(wp.x & 0xffff), w1 = b2f(wp.x >> 16), w2 = b2f(wp.y & 0xffff), w3 = b2f(wp.y >> 16);
      float g0 = acc[0]*SA*w0, g1 = acc[1]*SA*w1, g2 = acc[2]*SA*w2, g3 = acc[3]*SA*w3;
      st4(&s_mvp[0*2304 + mrow * 72 + n0 + g * 4], g0*yvm0, g1*yvm0, g2*yvm0, g3*yvm0);
      st4(&s_mvp[1*2304 + mrow * 72 + n0 + g * 4], g0*yvm1, g1*yvm1, g2*yvm1, g3*yvm1);
      st4(&s_mvp[2*2304 + mrow * 72 + n0 + g * 4], g0*yvm2, g1*yvm2, g2*yvm2, g3*yvm2);
    }
    __syncthreads();

    // ---- TP group 2: vv + vs ----
    const float SB = ed ? RS32 : RS64;      // scale for s_b / v_b
    if (!ed) { stage_wT<64>(P.Wn_vv, 64, s_W, 72, tid); stage_wT<32>(P.Wn_vs, 64, s_W + 4608, 72, tid); }
    else     { stage_wT<64>(P.We_vv, 32, s_W, 40, tid); stage_wT<32>(P.We_vs, 32, s_W + 2560, 40, tid); }
    __syncthreads();
    for (int nt = 0; nt < 2; ++nt) {        // s_b -> msp[:, 64:128]
      int n0 = nh * 32 + nt * 16;
      f32x4 acc = ed ? gemm_one<1>(s_W, 40, s_dot, 72, n0, c, gofs, mrow, (f32x4){0,0,0,0})
                     : gemm_one<2>(s_W, 72, s_dot, 72, n0, c, gofs, mrow, (f32x4){0,0,0,0});
      uint2 wp = *(const uint2*)&s_w[mrow * 200 + 64 + n0 + g * 4];
      float w0 = b2f(wp.x & 0xffff), w1 = b2f(wp.x >> 16), w2 = b2f(wp.y & 0xffff), w3 = b2f(wp.y >> 16);
      st4(&s_msp[mrow * 136 + 64 + n0 + g * 4], acc[0]*SB*w0, acc[1]*SB*w1, acc[2]*SB*w2, acc[3]*SB*w3);
    }
    for (int i = 0; i < 3; ++i) {           // v_b -> mvp[i][:, 32:64]
      int n0 = nh * 16;
      const ushort* Wt = s_W + (ed ? 2560 : 4608);
      f32x4 acc = ed ? gemm_one<1>(Wt, 40, s_xv + i*2304, 72, n0, c, gofs, mrow, (f32x4){0,0,0,0})
                     : gemm_one<2>(Wt, 72, s_xv + i*2304, 72, n0, c, gofs, mrow, (f32x4){0,0,0,0});
      uint2 wp = *(const uint2*)&s_w[mrow * 200 + 160 + n0 + g * 4];
      float w0 = b2f(wp.x & 0xffff), w1 = b2f(wp.x >> 16), w2 = b2f(wp.y & 0xffff), w3 = b2f(wp.y >> 16);
      st4(&s_mvp[i*2304 + mrow * 72 + 32 + n0 + g * 4],
          acc[0]*ysm*SB*w0, acc[1]*ysm*SB*w1, acc[2]*ysm*SB*w2, acc[3]*ysm*SB*w3);
    }
    __syncthreads();

    // ---- scale-linear ----
    if (!ed) { stage_wT<64>(P.Wns_s, 128, s_W, 136, tid); stage_wT<32>(P.Wns_v, 64, s_W + 8704, 72, tid); }
    else     { stage_wT<64>(P.Wes_s, 128, s_W, 136, tid); stage_wT<32>(P.Wes_v, 64, s_W + 8704, 72, tid); }
    __syncthreads();
    for (int nt = 0; nt < 2; ++nt) {
      int n0 = nh * 32 + nt * 16;
      f32x4 acc = gemm_one<4>(s_W, 136, s_msp, 136, n0, c, gofs, mrow, (f32x4){0,0,0,0});
      st4(&s_ns[mrow * 72 + n0 + g * 4], acc[0]*RS128, acc[1]*RS128, acc[2]*RS128, acc[3]*RS128);
    }
    for (int i = 0; i < 3; ++i) {
      int n0 = nh * 16;
      f32x4 acc = gemm_one<2>(s_W + 8704, 72, s_mvp + i*2304, 72, n0, c, gofs, mrow, (f32x4){0,0,0,0});
      st4(&s_nv[i*1280 + mrow * 40 + n0 + g * 4], acc[0]*RS64, acc[1]*RS64, acc[2]*RS64, acc[3]*RS64);
    }
    __syncthreads();

    // ---- output linear (accumulate in registers) ----
    if (!ed) { stage_wT<64>(P.Wno_s, 64, s_W, 72, tid); stage_wT<32>(P.Wno_v, 32, s_W + 4608, 40, tid); }
    else     { stage_wT<64>(P.Weo_s, 64, s_W, 72, tid); stage_wT<32>(P.Weo_v, 32, s_W + 4608, 40, tid); }
    __syncthreads();
    for (int nt = 0; nt < 2; ++nt) {
      int n0 = nh * 32 + nt * 16;
      oacc_s[nt] = gemm_one<2>(s_W, 72, s_ns, 72, n0, c, gofs, mrow, oacc_s[nt]);
    }
    for (int i = 0; i < 3; ++i) {
      int n0 = nh * 16;
      oacc_v[i] = gemm_one<1>(s_W + 4608, 40, s_nv + i*1280, 40, n0, c, gofs, mrow, oacc_v[i]);
    }
    __syncthreads();
  }

  // ---------------- final store ----------------
  const size_t orow = (size_t)(e0 + mrow) * 160;
  for (int nt = 0; nt < 2; ++nt) {
    int n0 = nh * 32 + nt * 16;
    float4 o;
    o.x = oacc_s[nt][0]*RS64; o.y = oacc_s[nt][1]*RS64;
    o.z = oacc_s[nt][2]*RS64; o.w = oacc_s[nt][3]*RS64;
    *(float4*)(P.out + orow + n0 + g * 4) = o;
  }
  {
    int n0 = nh * 16;
#pragma unroll
    for (int i = 0; i < 3; ++i)
#pragma unroll
      for (int r = 0; r < 4; ++r)
        P.out[orow + 64 + (size_t)(n0 + g * 4 + r) * 3 + i] = oacc_v[i][r] * RS32;
  }
}

extern "C" void kernel_launch(void* const* d_in, const int* in_sizes, int n_in,
                              void* d_out, int out_size, void* d_ws, size_t ws_size,
                              hipStream_t stream) {
  Ptrs P;
  P.src   = (const float*)d_in[0];
  P.dst   = (const float*)d_in[1];
  P.ef    = (const float*)d_in[2];
  P.env   = (const float*)d_in[3];
  P.scal  = (const float*)d_in[4];
  P.Wn_ss = (const float*)d_in[5];
  P.Wn_vv = (const float*)d_in[6];
  P.Wn_sv = (const float*)d_in[7];
  P.Wn_vs = (const float*)d_in[8];
  P.We_ss = (const float*)d_in[9];
  P.We_vv = (const float*)d_in[10];
  P.We_sv = (const float*)d_in[11];
  P.We_vs = (const float*)d_in[12];
  P.Wns_s = (const float*)d_in[13];
  P.Wns_v = (const float*)d_in[14];
  P.Wes_s = (const float*)d_in[15];
  P.Wes_v = (const float*)d_in[16];
  P.Wno_s = (const float*)d_in[17];
  P.Wno_v = (const float*)d_in[18];
  P.Weo_s = (const float*)d_in[19];
  P.Weo_v = (const float*)d_in[20];
  P.Wnm1  = (const float*)d_in[21];
  P.Wnm2  = (const float*)d_in[22];
  P.Wnm3  = (const float*)d_in[23];
  P.Wem1  = (const float*)d_in[24];
  P.Wem2  = (const float*)d_in[25];
  P.Wem3  = (const float*)d_in[26];
  P.out   = (float*)d_out;

  const int E = in_sizes[0] / 160;  // 131072
  mp_kernel<<<dim3(E / 32), dim3(256), 0, stream>>>(P);
}

// Round 4
// 348.399 us; speedup vs baseline: 52.1886x; 2.2026x over previous
//
#include <hip/hip_runtime.h>

// R4: R3 with fragment-tile offset bug fixed (tile base = t*KS*512 ushorts).
// Fused MFMA bf16 pipeline, weights pre-packed to fragment-major bf16 in ws.
// 32 edges/block, 256 threads (4 waves), 78 KB LDS -> 2 blocks/CU.

typedef short  bf16x8 __attribute__((ext_vector_type(8)));
typedef float  f32x4  __attribute__((ext_vector_type(4)));

constexpr float BETA  = 1.6791767f;
constexpr float RS128 = 0.088388347648318447f;
constexpr float RS64  = 0.125f;
constexpr float RS32  = 0.176776695296636881f;
constexpr float RSQ3  = 0.577350269189625842f;

// ws offsets (ushort units) for fragment-packed weights
enum : int {
  O_nm1 = 0,      O_nm2 = 4096,   O_nm3 = 8192,
  O_em1 = 20480,  O_em2 = 24576,  O_em3 = 28672,
  O_nss = 40960,  O_nsv = 49152,  O_nvv = 53248,  O_nvs = 57344,
  O_ess = 59392,  O_esv = 63488,  O_evv = 65536,  O_evs = 67584,
  O_nss2= 68608,  O_nsv2= 76800,  O_ess2= 78848,  O_esv2= 87040,
  O_nos = 89088,  O_nov = 93184,  O_eos = 94208,  O_eov = 98304,
  W_TOTAL = 99328
};

struct Ptrs {
  const float *src, *dst, *ef, *env, *scal;
  const ushort* wf;   // packed weights in ws
  float *out;
};

struct PrepArgs {
  const float* src[22];
  int K[22], N[22], ofs[22];
  ushort* dst;
};

__device__ __forceinline__ ushort f2b(float x) {
  union { float f; unsigned u; } v; v.f = x;
  unsigned r = v.u + 0x7fffu + ((v.u >> 16) & 1u);
  return (ushort)(r >> 16);
}
__device__ __forceinline__ float b2f(unsigned h) {
  union { unsigned u; float f; } v; v.u = h << 16; return v.f;
}
__device__ __forceinline__ void st4(ushort* p, float a0, float a1, float a2, float a3) {
  uint2 v;
  v.x = (unsigned)f2b(a0) | ((unsigned)f2b(a1) << 16);
  v.y = (unsigned)f2b(a2) | ((unsigned)f2b(a3) << 16);
  *(uint2*)p = v;
}

// ---------------- prep: pack W^T into fragment-major bf16 ----------------
// group gi = t*(64*KS) + ks*64 + lane  ->  ushort offset gi*8
// holds W^T[n = t*16 + (lane&15)][k = ks*32 + (lane>>4)*8 + 0..7]
__global__ __launch_bounds__(256) void prep_kernel(PrepArgs A) {
  const int mat = blockIdx.x;
  const float* __restrict__ src = A.src[mat];
  const int K = A.K[mat], N = A.N[mat], KS = K >> 5;
  ushort* dst = A.dst + A.ofs[mat];
  const int total = (N * K) >> 3;
  for (int gi = threadIdx.x; gi < total; gi += 256) {
    int t = gi / (64 * KS), r = gi - t * 64 * KS;
    int ks = r >> 6, lane = r & 63;
    int c = lane & 15, g = lane >> 4;
    int n = t * 16 + c, k0 = ks * 32 + g * 8;
    ushort v[8];
#pragma unroll
    for (int j = 0; j < 8; ++j) v[j] = f2b(src[(size_t)(k0 + j) * N + n]);
    *(uint4*)(dst + (size_t)gi * 8) = *(const uint4*)v;
  }
}

// one 16x16 tile: A-fragments from packed global, B from LDS edge-major
template<int KS>
__device__ __forceinline__ f32x4 gemm_one(const ushort* __restrict__ wf,
                                          const ushort* __restrict__ X, int xst,
                                          int n0, int lane, int gofs, int mrow, f32x4 acc) {
  const ushort* wp = wf + ((size_t)(n0 >> 4) * KS * 512 + lane * 8);  // FIX: *512
#pragma unroll
  for (int ks = 0; ks < KS; ++ks) {
    bf16x8 a = *(const bf16x8*)(wp + ks * 512);
    bf16x8 b = *(const bf16x8*)(X + mrow * xst + ks * 32 + gofs);
    acc = __builtin_amdgcn_mfma_f32_16x16x32_bf16(a, b, acc, 0, 0, 0);
  }
  return acc;
}

__global__ __launch_bounds__(256, 2) void mp_kernel(Ptrs P) {
  const int tid  = threadIdx.x;
  const int e0   = blockIdx.x * 32;
  const int lane = tid & 63, wid = tid >> 6;
  const int mt   = wid & 1,  nh  = wid >> 1;
  const int c    = lane & 15, g  = lane >> 4;
  const int gofs = g * 8;
  const int mrow = mt * 16 + c;
  const ushort* WF = P.wf;
  const f32x4 Z = (f32x4){0, 0, 0, 0};

  __shared__ float  s_env [32 * 4];        //   512 B
  __shared__ ushort s_scal[32 * 72];       //  4608 B
  __shared__ ushort s_xs  [32 * 136];      //  8704 B
  __shared__ ushort s_xv  [3 * 32 * 72];   // 13824 B
  __shared__ ushort s_dot [32 * 72];       //  4608 B
  __shared__ ushort s_w   [32 * 200];      // 12800 B
  __shared__ ushort s_msp [32 * 136];      //  8704 B
  __shared__ ushort s_mvp [3 * 32 * 72];   // 13824 B
  __shared__ ushort s_u   [6144];          // 12288 B: h0|h1  OR  ns|nv
  ushort* s_h0 = s_u;                      // [32][72]
  ushort* s_h1 = s_u + 2304;               // [32][72]
  ushort* s_ns = s_u;                      // [32][72]
  ushort* s_nv = s_u + 2304;               // [3][32][40]

  // ---------------- S0: stage env, scal, node tiles ----------------
  if (tid < 128) s_env[tid] = P.env[(size_t)e0 * 4 + tid];
  for (int idx = tid; idx < 32 * 16; idx += 256) {            // scal [32][64]
    int m = idx >> 4, q = idx & 15;
    float4 v = *(const float4*)(P.scal + (size_t)(e0 + m) * 64 + q * 4);
    st4(&s_scal[m * 72 + q * 4], v.x, v.y, v.z, v.w);
  }
  for (int idx = tid; idx < 32 * 32; idx += 256) {            // xs = [ss|ds]
    int m = idx >> 5, q = idx & 31;
    const float* basep = (q < 16) ? P.src : P.dst;
    float4 v = *(const float4*)(basep + (size_t)(e0 + m) * 160 + (q & 15) * 4);
    st4(&s_xs[m * 136 + q * 4], v.x, v.y, v.z, v.w);
  }
  for (int idx = tid; idx < 32 * 96; idx += 256) {            // sv -> xv[i][m][u]
    int m = idx / 96, j = idx - m * 96, u = j / 3, i = j - u * 3;
    s_xv[i * 2304 + m * 72 + u] = f2b(P.src[(size_t)(e0 + m) * 160 + 64 + j]);
  }
  for (int idx = tid; idx < 32 * 96; idx += 256) {            // dv -> xv[i][m][32+u]
    int m = idx / 96, j = idx - m * 96, u = j / 3, i = j - u * 3;
    s_xv[i * 2304 + m * 72 + 32 + u] = f2b(P.dst[(size_t)(e0 + m) * 160 + 64 + j]);
  }
  for (int idx = tid; idx < 32 * 64; idx += 256) {            // node dot
    int m = idx >> 6, u = idx & 63;
    const float* basep = (u < 32) ? P.src : P.dst;
    const float* v3 = basep + (size_t)(e0 + m) * 160 + 64 + (u & 31) * 3;
    const float* yv = P.env + (size_t)(e0 + m) * 4 + 1;
    s_dot[m * 72 + u] = f2b((v3[0]*yv[0] + v3[1]*yv[1] + v3[2]*yv[2]) * RSQ3);
  }
  __syncthreads();

  f32x4 oacc_s[2]; f32x4 oacc_v[3];
  for (int t = 0; t < 2; ++t) oacc_s[t] = Z;
  for (int i = 0; i < 3; ++i) oacc_v[i] = Z;

  const float ysm  = s_env[mrow * 4 + 0];
  const float yvm0 = s_env[mrow * 4 + 1];
  const float yvm1 = s_env[mrow * 4 + 2];
  const float yvm2 = s_env[mrow * 4 + 3];

  for (int path = 0; path < 2; ++path) {
    const bool ed = (path == 1);

    // ---- MLP1 ----
    {
      const ushort* wf = WF + (ed ? O_em1 : O_nm1);
      for (int nt = 0; nt < 2; ++nt) {
        int n0 = nh * 32 + nt * 16;
        f32x4 acc = gemm_one<2>(wf, s_scal, 72, n0, lane, gofs, mrow, Z);
        float o[4];
#pragma unroll
        for (int r = 0; r < 4; ++r) { float z = acc[r]*0.125f; o[r] = BETA*z/(1.f+__expf(-z)); }
        st4(&s_h0[mrow * 72 + n0 + g * 4], o[0], o[1], o[2], o[3]);
      }
    }
    __syncthreads();
    // ---- MLP2 ----
    {
      const ushort* wf = WF + (ed ? O_em2 : O_nm2);
      for (int nt = 0; nt < 2; ++nt) {
        int n0 = nh * 32 + nt * 16;
        f32x4 acc = gemm_one<2>(wf, s_h0, 72, n0, lane, gofs, mrow, Z);
        float o[4];
#pragma unroll
        for (int r = 0; r < 4; ++r) { float z = acc[r]*0.125f; o[r] = BETA*z/(1.f+__expf(-z)); }
        st4(&s_h1[mrow * 72 + n0 + g * 4], o[0], o[1], o[2], o[3]);
      }
    }
    __syncthreads();
    // ---- MLP3: w ----
    {
      const ushort* wf = WF + (ed ? O_em3 : O_nm3);
      for (int nt = 0; nt < 6; ++nt) {
        int n0 = nh * 96 + nt * 16;
        f32x4 acc = gemm_one<2>(wf, s_h1, 72, n0, lane, gofs, mrow, Z);
        st4(&s_w[mrow * 200 + n0 + g * 4],
            acc[0]*0.125f, acc[1]*0.125f, acc[2]*0.125f, acc[3]*0.125f);
      }
    }
    __syncthreads();

    // ---- TP (both groups) ----
    {
      const float SA = ed ? RS64 : RS128;
      const float SB = ed ? RS32 : RS64;
      const ushort* wss = WF + (ed ? O_ess : O_nss);
      for (int nt = 0; nt < 2; ++nt) {          // s_a -> msp[:, :64]
        int n0 = nh * 32 + nt * 16;
        f32x4 acc = ed ? gemm_one<2>(wss, s_xs, 136, n0, lane, gofs, mrow, Z)
                       : gemm_one<4>(wss, s_xs, 136, n0, lane, gofs, mrow, Z);
        uint2 wp = *(const uint2*)&s_w[mrow * 200 + n0 + g * 4];
        float w0 = b2f(wp.x & 0xffff), w1 = b2f(wp.x >> 16), w2 = b2f(wp.y & 0xffff), w3 = b2f(wp.y >> 16);
        st4(&s_msp[mrow * 136 + n0 + g * 4],
            acc[0]*ysm*SA*w0, acc[1]*ysm*SA*w1, acc[2]*ysm*SA*w2, acc[3]*ysm*SA*w3);
      }
      {                                          // v_a -> mvp[i][:, :32]
        int n0 = nh * 16;
        const ushort* wsv = WF + (ed ? O_esv : O_nsv);
        f32x4 acc = ed ? gemm_one<2>(wsv, s_xs, 136, n0, lane, gofs, mrow, Z)
                       : gemm_one<4>(wsv, s_xs, 136, n0, lane, gofs, mrow, Z);
        uint2 wp = *(const uint2*)&s_w[mrow * 200 + 128 + n0 + g * 4];
        float w0 = b2f(wp.x & 0xffff), w1 = b2f(wp.x >> 16), w2 = b2f(wp.y & 0xffff), w3 = b2f(wp.y >> 16);
        float g0 = acc[0]*SA*w0, g1 = acc[1]*SA*w1, g2 = acc[2]*SA*w2, g3 = acc[3]*SA*w3;
        st4(&s_mvp[0*2304 + mrow * 72 + n0 + g * 4], g0*yvm0, g1*yvm0, g2*yvm0, g3*yvm0);
        st4(&s_mvp[1*2304 + mrow * 72 + n0 + g * 4], g0*yvm1, g1*yvm1, g2*yvm1, g3*yvm1);
        st4(&s_mvp[2*2304 + mrow * 72 + n0 + g * 4], g0*yvm2, g1*yvm2, g2*yvm2, g3*yvm2);
      }
      const ushort* wvv = WF + (ed ? O_evv : O_nvv);
      for (int nt = 0; nt < 2; ++nt) {          // s_b -> msp[:, 64:128]
        int n0 = nh * 32 + nt * 16;
        f32x4 acc = ed ? gemm_one<1>(wvv, s_dot, 72, n0, lane, gofs, mrow, Z)
                       : gemm_one<2>(wvv, s_dot, 72, n0, lane, gofs, mrow, Z);
        uint2 wp = *(const uint2*)&s_w[mrow * 200 + 64 + n0 + g * 4];
        float w0 = b2f(wp.x & 0xffff), w1 = b2f(wp.x >> 16), w2 = b2f(wp.y & 0xffff), w3 = b2f(wp.y >> 16);
        st4(&s_msp[mrow * 136 + 64 + n0 + g * 4],
            acc[0]*SB*w0, acc[1]*SB*w1, acc[2]*SB*w2, acc[3]*SB*w3);
      }
      {                                          // v_b -> mvp[i][:, 32:64]
        int n0 = nh * 16;
        const ushort* wvs = WF + (ed ? O_evs : O_nvs);
#pragma unroll
        for (int i = 0; i < 3; ++i) {
          f32x4 acc = ed ? gemm_one<1>(wvs, s_xv + i*2304, 72, n0, lane, gofs, mrow, Z)
                         : gemm_one<2>(wvs, s_xv + i*2304, 72, n0, lane, gofs, mrow, Z);
          uint2 wp = *(const uint2*)&s_w[mrow * 200 + 160 + n0 + g * 4];
          float w0 = b2f(wp.x & 0xffff), w1 = b2f(wp.x >> 16), w2 = b2f(wp.y & 0xffff), w3 = b2f(wp.y >> 16);
          st4(&s_mvp[i*2304 + mrow * 72 + 32 + n0 + g * 4],
              acc[0]*ysm*SB*w0, acc[1]*ysm*SB*w1, acc[2]*ysm*SB*w2, acc[3]*ysm*SB*w3);
        }
      }
    }
    __syncthreads();

    // ---- scale-linear ----
    {
      const ushort* ws_s = WF + (ed ? O_ess2 : O_nss2);
      for (int nt = 0; nt < 2; ++nt) {
        int n0 = nh * 32 + nt * 16;
        f32x4 acc = gemm_one<4>(ws_s, s_msp, 136, n0, lane, gofs, mrow, Z);
        st4(&s_ns[mrow * 72 + n0 + g * 4], acc[0]*RS128, acc[1]*RS128, acc[2]*RS128, acc[3]*RS128);
      }
      const ushort* ws_v = WF + (ed ? O_esv2 : O_nsv2);
      int n0 = nh * 16;
#pragma unroll
      for (int i = 0; i < 3; ++i) {
        f32x4 acc = gemm_one<2>(ws_v, s_mvp + i*2304, 72, n0, lane, gofs, mrow, Z);
        st4(&s_nv[i*1280 + mrow * 40 + n0 + g * 4], acc[0]*RS64, acc[1]*RS64, acc[2]*RS64, acc[3]*RS64);
      }
    }
    __syncthreads();

    // ---- output linear (accumulate) + edge restage on node pass ----
    {
      const ushort* wo_s = WF + (ed ? O_eos : O_nos);
      for (int nt = 0; nt < 2; ++nt) {
        int n0 = nh * 32 + nt * 16;
        oacc_s[nt] = gemm_one<2>(wo_s, s_ns, 72, n0, lane, gofs, mrow, oacc_s[nt]);
      }
      const ushort* wo_v = WF + (ed ? O_eov : O_nov);
      int n0 = nh * 16;
#pragma unroll
      for (int i = 0; i < 3; ++i)
        oacc_v[i] = gemm_one<1>(wo_v, s_nv + i*1280, 40, n0, lane, gofs, mrow, oacc_v[i]);
    }
    if (!ed) {
      // restage edge tiles (xs/xv/dot dead after node TP)
      for (int idx = tid; idx < 32 * 16; idx += 256) {
        int m = idx >> 4, q = idx & 15;
        float4 v = *(const float4*)(P.ef + (size_t)(e0 + m) * 160 + q * 4);
        st4(&s_xs[m * 136 + q * 4], v.x, v.y, v.z, v.w);
      }
      for (int idx = tid; idx < 32 * 96; idx += 256) {
        int m = idx / 96, j = idx - m * 96, u = j / 3, i = j - u * 3;
        s_xv[i * 2304 + m * 72 + u] = f2b(P.ef[(size_t)(e0 + m) * 160 + 64 + j]);
      }
      for (int idx = tid; idx < 32 * 32; idx += 256) {
        int m = idx >> 5, u = idx & 31;
        const float* v3 = P.ef + (size_t)(e0 + m) * 160 + 64 + u * 3;
        const float* yv = P.env + (size_t)(e0 + m) * 4 + 1;
        s_dot[m * 72 + u] = f2b((v3[0]*yv[0] + v3[1]*yv[1] + v3[2]*yv[2]) * RSQ3);
      }
      __syncthreads();
    }
  }

  // ---------------- final store ----------------
  const size_t orow = (size_t)(e0 + mrow) * 160;
  for (int nt = 0; nt < 2; ++nt) {
    int n0 = nh * 32 + nt * 16;
    float4 o;
    o.x = oacc_s[nt][0]*RS64; o.y = oacc_s[nt][1]*RS64;
    o.z = oacc_s[nt][2]*RS64; o.w = oacc_s[nt][3]*RS64;
    *(float4*)(P.out + orow + n0 + g * 4) = o;
  }
  {
    int n0 = nh * 16;
#pragma unroll
    for (int i = 0; i < 3; ++i)
#pragma unroll
      for (int r = 0; r < 4; ++r)
        P.out[orow + 64 + (size_t)(n0 + g * 4 + r) * 3 + i] = oacc_v[i][r] * RS32;
  }
}

extern "C" void kernel_launch(void* const* d_in, const int* in_sizes, int n_in,
                              void* d_out, int out_size, void* d_ws, size_t ws_size,
                              hipStream_t stream) {
  PrepArgs A;
  // order matches offset table
  const int src_idx[22] = {21,22,23, 24,25,26, 5,7,6,8, 9,11,10,12, 13,14, 15,16, 17,18, 19,20};
  const int Ks[22] = {64,64,64, 64,64,64, 128,128,64,64, 64,64,32,32, 128,64, 128,64, 64,32, 64,32};
  const int Ns[22] = {64,64,192, 64,64,192, 64,32,64,32, 64,32,64,32, 64,32, 64,32, 64,32, 64,32};
  const int Os[22] = {O_nm1,O_nm2,O_nm3, O_em1,O_em2,O_em3,
                      O_nss,O_nsv,O_nvv,O_nvs, O_ess,O_esv,O_evv,O_evs,
                      O_nss2,O_nsv2, O_ess2,O_esv2, O_nos,O_nov, O_eos,O_eov};
  for (int i = 0; i < 22; ++i) {
    A.src[i] = (const float*)d_in[src_idx[i]];
    A.K[i] = Ks[i]; A.N[i] = Ns[i]; A.ofs[i] = Os[i];
  }
  A.dst = (ushort*)d_ws;
  prep_kernel<<<dim3(22), dim3(256), 0, stream>>>(A);

  Ptrs P;
  P.src  = (const float*)d_in[0];
  P.dst  = (const float*)d_in[1];
  P.ef   = (const float*)d_in[2];
  P.env  = (const float*)d_in[3];
  P.scal = (const float*)d_in[4];
  P.wf   = (const ushort*)d_ws;
  P.out  = (float*)d_out;

  const int E = in_sizes[0] / 160;  // 131072
  mp_kernel<<<dim3(E / 32), dim3(256), 0, stream>>>(P);
}

// Round 5
// 316.149 us; speedup vs baseline: 57.5124x; 1.1020x over previous
//
#include <hip/hip_runtime.h>

// R5: R4 dataflow, 512 threads (8 waves) per 32-edge block.
// 2 blocks/CU (156KB LDS) -> 16 waves/CU. Tile work spread over 8 waves:
// mt = wid&1 (edge half), nq = wid>>1 (n-tile group).

typedef short  bf16x8 __attribute__((ext_vector_type(8)));
typedef float  f32x4  __attribute__((ext_vector_type(4)));

constexpr float BETA  = 1.6791767f;
constexpr float RS128 = 0.088388347648318447f;
constexpr float RS64  = 0.125f;
constexpr float RS32  = 0.176776695296636881f;
constexpr float RSQ3  = 0.577350269189625842f;

// ws offsets (ushort units) for fragment-packed weights
enum : int {
  O_nm1 = 0,      O_nm2 = 4096,   O_nm3 = 8192,
  O_em1 = 20480,  O_em2 = 24576,  O_em3 = 28672,
  O_nss = 40960,  O_nsv = 49152,  O_nvv = 53248,  O_nvs = 57344,
  O_ess = 59392,  O_esv = 63488,  O_evv = 65536,  O_evs = 67584,
  O_nss2= 68608,  O_nsv2= 76800,  O_ess2= 78848,  O_esv2= 87040,
  O_nos = 89088,  O_nov = 93184,  O_eos = 94208,  O_eov = 98304,
  W_TOTAL = 99328
};

struct Ptrs {
  const float *src, *dst, *ef, *env, *scal;
  const ushort* wf;
  float *out;
};

struct PrepArgs {
  const float* src[22];
  int K[22], N[22], ofs[22];
  ushort* dst;
};

__device__ __forceinline__ ushort f2b(float x) {
  union { float f; unsigned u; } v; v.f = x;
  unsigned r = v.u + 0x7fffu + ((v.u >> 16) & 1u);
  return (ushort)(r >> 16);
}
__device__ __forceinline__ float b2f(unsigned h) {
  union { unsigned u; float f; } v; v.u = h << 16; return v.f;
}
__device__ __forceinline__ void st4(ushort* p, float a0, float a1, float a2, float a3) {
  uint2 v;
  v.x = (unsigned)f2b(a0) | ((unsigned)f2b(a1) << 16);
  v.y = (unsigned)f2b(a2) | ((unsigned)f2b(a3) << 16);
  *(uint2*)p = v;
}

// ---------------- prep: pack W^T into fragment-major bf16 ----------------
__global__ __launch_bounds__(256) void prep_kernel(PrepArgs A) {
  const int mat = blockIdx.x;
  const float* __restrict__ src = A.src[mat];
  const int K = A.K[mat], N = A.N[mat], KS = K >> 5;
  ushort* dst = A.dst + A.ofs[mat];
  const int total = (N * K) >> 3;
  for (int gi = threadIdx.x; gi < total; gi += 256) {
    int t = gi / (64 * KS), r = gi - t * 64 * KS;
    int ks = r >> 6, lane = r & 63;
    int cc = lane & 15, gg = lane >> 4;
    int n = t * 16 + cc, k0 = ks * 32 + gg * 8;
    ushort v[8];
#pragma unroll
    for (int j = 0; j < 8; ++j) v[j] = f2b(src[(size_t)(k0 + j) * N + n]);
    *(uint4*)(dst + (size_t)gi * 8) = *(const uint4*)v;
  }
}

template<int KS>
__device__ __forceinline__ f32x4 gemm_one(const ushort* __restrict__ wf,
                                          const ushort* __restrict__ X, int xst,
                                          int n0, int lane, int gofs, int mrow, f32x4 acc) {
  const ushort* wp = wf + ((size_t)(n0 >> 4) * KS * 512 + lane * 8);
#pragma unroll
  for (int ks = 0; ks < KS; ++ks) {
    bf16x8 a = *(const bf16x8*)(wp + ks * 512);
    bf16x8 b = *(const bf16x8*)(X + mrow * xst + ks * 32 + gofs);
    acc = __builtin_amdgcn_mfma_f32_16x16x32_bf16(a, b, acc, 0, 0, 0);
  }
  return acc;
}

__global__ __launch_bounds__(512, 4) void mp_kernel(Ptrs P) {
  const int tid  = threadIdx.x;
  const int e0   = blockIdx.x * 32;
  const int lane = tid & 63, wid = tid >> 6;
  const int mt   = wid & 1,  nq  = wid >> 1;   // nq 0..3
  const int c    = lane & 15, g  = lane >> 4;
  const int gofs = g * 8;
  const int mrow = mt * 16 + c;
  const ushort* WF = P.wf;
  const f32x4 Z = (f32x4){0, 0, 0, 0};

  __shared__ float  s_env [32 * 4];
  __shared__ ushort s_scal[32 * 72];
  __shared__ ushort s_xs  [32 * 136];
  __shared__ ushort s_xv  [3 * 32 * 72];
  __shared__ ushort s_dot [32 * 72];
  __shared__ ushort s_w   [32 * 200];
  __shared__ ushort s_msp [32 * 136];
  __shared__ ushort s_mvp [3 * 32 * 72];
  __shared__ ushort s_u   [6144];
  ushort* s_h0 = s_u;
  ushort* s_h1 = s_u + 2304;
  ushort* s_ns = s_u;
  ushort* s_nv = s_u + 2304;

  // ---------------- S0: stage env, scal, node tiles ----------------
  if (tid < 128) s_env[tid] = P.env[(size_t)e0 * 4 + tid];
  for (int idx = tid; idx < 32 * 16; idx += 512) {
    int m = idx >> 4, q = idx & 15;
    float4 v = *(const float4*)(P.scal + (size_t)(e0 + m) * 64 + q * 4);
    st4(&s_scal[m * 72 + q * 4], v.x, v.y, v.z, v.w);
  }
  for (int idx = tid; idx < 32 * 32; idx += 512) {
    int m = idx >> 5, q = idx & 31;
    const float* basep = (q < 16) ? P.src : P.dst;
    float4 v = *(const float4*)(basep + (size_t)(e0 + m) * 160 + (q & 15) * 4);
    st4(&s_xs[m * 136 + q * 4], v.x, v.y, v.z, v.w);
  }
  for (int idx = tid; idx < 32 * 96; idx += 512) {
    int m = idx / 96, j = idx - m * 96, u = j / 3, i = j - u * 3;
    s_xv[i * 2304 + m * 72 + u] = f2b(P.src[(size_t)(e0 + m) * 160 + 64 + j]);
  }
  for (int idx = tid; idx < 32 * 96; idx += 512) {
    int m = idx / 96, j = idx - m * 96, u = j / 3, i = j - u * 3;
    s_xv[i * 2304 + m * 72 + 32 + u] = f2b(P.dst[(size_t)(e0 + m) * 160 + 64 + j]);
  }
  for (int idx = tid; idx < 32 * 64; idx += 512) {
    int m = idx >> 6, u = idx & 63;
    const float* basep = (u < 32) ? P.src : P.dst;
    const float* v3 = basep + (size_t)(e0 + m) * 160 + 64 + (u & 31) * 3;
    const float* yv = P.env + (size_t)(e0 + m) * 4 + 1;
    s_dot[m * 72 + u] = f2b((v3[0]*yv[0] + v3[1]*yv[1] + v3[2]*yv[2]) * RSQ3);
  }
  __syncthreads();

  f32x4 oacc_s = Z, oacc_v0 = Z, oacc_v1 = Z;

  const float ysm  = s_env[mrow * 4 + 0];
  const float yvm0 = s_env[mrow * 4 + 1];
  const float yvm1 = s_env[mrow * 4 + 2];
  const float yvm2 = s_env[mrow * 4 + 3];

  for (int path = 0; path < 2; ++path) {
    const bool ed = (path == 1);

    // ---- MLP1 ----
    {
      const ushort* wf = WF + (ed ? O_em1 : O_nm1);
      int n0 = nq * 16;
      f32x4 acc = gemm_one<2>(wf, s_scal, 72, n0, lane, gofs, mrow, Z);
      float o[4];
#pragma unroll
      for (int r = 0; r < 4; ++r) { float z = acc[r]*0.125f; o[r] = BETA*z/(1.f+__expf(-z)); }
      st4(&s_h0[mrow * 72 + n0 + g * 4], o[0], o[1], o[2], o[3]);
    }
    __syncthreads();
    // ---- MLP2 ----
    {
      const ushort* wf = WF + (ed ? O_em2 : O_nm2);
      int n0 = nq * 16;
      f32x4 acc = gemm_one<2>(wf, s_h0, 72, n0, lane, gofs, mrow, Z);
      float o[4];
#pragma unroll
      for (int r = 0; r < 4; ++r) { float z = acc[r]*0.125f; o[r] = BETA*z/(1.f+__expf(-z)); }
      st4(&s_h1[mrow * 72 + n0 + g * 4], o[0], o[1], o[2], o[3]);
    }
    __syncthreads();
    // ---- MLP3: w ----
    {
      const ushort* wf = WF + (ed ? O_em3 : O_nm3);
#pragma unroll
      for (int j = 0; j < 3; ++j) {
        int n0 = (nq + 4 * j) * 16;
        f32x4 acc = gemm_one<2>(wf, s_h1, 72, n0, lane, gofs, mrow, Z);
        st4(&s_w[mrow * 200 + n0 + g * 4],
            acc[0]*0.125f, acc[1]*0.125f, acc[2]*0.125f, acc[3]*0.125f);
      }
    }
    __syncthreads();

    // ---- TP: 16 tile-units over 8 waves (u = nq + 4j) ----
    {
      const float SA = ed ? RS64 : RS128;
      const float SB = ed ? RS32 : RS64;
      const ushort* wss = WF + (ed ? O_ess : O_nss);
      const ushort* wsv = WF + (ed ? O_esv : O_nsv);
      const ushort* wvv = WF + (ed ? O_evv : O_nvv);
      const ushort* wvs = WF + (ed ? O_evs : O_nvs);
#pragma unroll
      for (int j = 0; j < 4; ++j) {
        int u = nq + 4 * j;
        if (u < 4) {                       // s_a -> msp[:, :64]
          int n0 = u * 16;
          f32x4 acc = ed ? gemm_one<2>(wss, s_xs, 136, n0, lane, gofs, mrow, Z)
                         : gemm_one<4>(wss, s_xs, 136, n0, lane, gofs, mrow, Z);
          uint2 wp = *(const uint2*)&s_w[mrow * 200 + n0 + g * 4];
          float w0 = b2f(wp.x & 0xffff), w1 = b2f(wp.x >> 16), w2 = b2f(wp.y & 0xffff), w3 = b2f(wp.y >> 16);
          st4(&s_msp[mrow * 136 + n0 + g * 4],
              acc[0]*ysm*SA*w0, acc[1]*ysm*SA*w1, acc[2]*ysm*SA*w2, acc[3]*ysm*SA*w3);
        } else if (u < 6) {                // v_a -> mvp[i][:, :32]
          int n0 = (u - 4) * 16;
          f32x4 acc = ed ? gemm_one<2>(wsv, s_xs, 136, n0, lane, gofs, mrow, Z)
                         : gemm_one<4>(wsv, s_xs, 136, n0, lane, gofs, mrow, Z);
          uint2 wp = *(const uint2*)&s_w[mrow * 200 + 128 + n0 + g * 4];
          float w0 = b2f(wp.x & 0xffff), w1 = b2f(wp.x >> 16), w2 = b2f(wp.y & 0xffff), w3 = b2f(wp.y >> 16);
          float g0 = acc[0]*SA*w0, g1 = acc[1]*SA*w1, g2 = acc[2]*SA*w2, g3 = acc[3]*SA*w3;
          st4(&s_mvp[0*2304 + mrow * 72 + n0 + g * 4], g0*yvm0, g1*yvm0, g2*yvm0, g3*yvm0);
          st4(&s_mvp[1*2304 + mrow * 72 + n0 + g * 4], g0*yvm1, g1*yvm1, g2*yvm1, g3*yvm1);
          st4(&s_mvp[2*2304 + mrow * 72 + n0 + g * 4], g0*yvm2, g1*yvm2, g2*yvm2, g3*yvm2);
        } else if (u < 10) {               // s_b -> msp[:, 64:128]
          int n0 = (u - 6) * 16;
          f32x4 acc = ed ? gemm_one<1>(wvv, s_dot, 72, n0, lane, gofs, mrow, Z)
                         : gemm_one<2>(wvv, s_dot, 72, n0, lane, gofs, mrow, Z);
          uint2 wp = *(const uint2*)&s_w[mrow * 200 + 64 + n0 + g * 4];
          float w0 = b2f(wp.x & 0xffff), w1 = b2f(wp.x >> 16), w2 = b2f(wp.y & 0xffff), w3 = b2f(wp.y >> 16);
          st4(&s_msp[mrow * 136 + 64 + n0 + g * 4],
              acc[0]*SB*w0, acc[1]*SB*w1, acc[2]*SB*w2, acc[3]*SB*w3);
        } else {                           // v_b -> mvp[i][:, 32:64]
          int q = u - 10, i = q >> 1, n0 = (q & 1) * 16;
          f32x4 acc = ed ? gemm_one<1>(wvs, s_xv + i*2304, 72, n0, lane, gofs, mrow, Z)
                         : gemm_one<2>(wvs, s_xv + i*2304, 72, n0, lane, gofs, mrow, Z);
          uint2 wp = *(const uint2*)&s_w[mrow * 200 + 160 + n0 + g * 4];
          float w0 = b2f(wp.x & 0xffff), w1 = b2f(wp.x >> 16), w2 = b2f(wp.y & 0xffff), w3 = b2f(wp.y >> 16);
          st4(&s_mvp[i*2304 + mrow * 72 + 32 + n0 + g * 4],
              acc[0]*ysm*SB*w0, acc[1]*ysm*SB*w1, acc[2]*ysm*SB*w2, acc[3]*ysm*SB*w3);
        }
      }
    }
    __syncthreads();

    // ---- scale-linear: 10 units over 8 waves ----
    {
      const ushort* ws_s = WF + (ed ? O_ess2 : O_nss2);
      const ushort* ws_v = WF + (ed ? O_esv2 : O_nsv2);
#pragma unroll
      for (int j = 0; j < 3; ++j) {
        int u = nq + 4 * j;
        if (u < 4) {
          int n0 = u * 16;
          f32x4 acc = gemm_one<4>(ws_s, s_msp, 136, n0, lane, gofs, mrow, Z);
          st4(&s_ns[mrow * 72 + n0 + g * 4], acc[0]*RS128, acc[1]*RS128, acc[2]*RS128, acc[3]*RS128);
        } else if (u < 10) {
          int q = u - 4, i = q >> 1, n0 = (q & 1) * 16;
          f32x4 acc = gemm_one<2>(ws_v, s_mvp + i*2304, 72, n0, lane, gofs, mrow, Z);
          st4(&s_nv[i*1280 + mrow * 40 + n0 + g * 4], acc[0]*RS64, acc[1]*RS64, acc[2]*RS64, acc[3]*RS64);
        }
      }
    }
    __syncthreads();

    // ---- output linear (accumulate in regs) + edge restage on node pass ----
    {
      const ushort* wo_s = WF + (ed ? O_eos : O_nos);
      const ushort* wo_v = WF + (ed ? O_eov : O_nov);
      {
        int n0 = nq * 16;
        oacc_s = gemm_one<2>(wo_s, s_ns, 72, n0, lane, gofs, mrow, oacc_s);
      }
      {
        int i = nq >> 1, n0 = (nq & 1) * 16;
        oacc_v0 = gemm_one<1>(wo_v, s_nv + i*1280, 40, n0, lane, gofs, mrow, oacc_v0);
      }
      if (nq < 2) {
        int n0 = (nq & 1) * 16;
        oacc_v1 = gemm_one<1>(wo_v, s_nv + 2*1280, 40, n0, lane, gofs, mrow, oacc_v1);
      }
    }
    if (!ed) {
      for (int idx = tid; idx < 32 * 16; idx += 512) {
        int m = idx >> 4, q = idx & 15;
        float4 v = *(const float4*)(P.ef + (size_t)(e0 + m) * 160 + q * 4);
        st4(&s_xs[m * 136 + q * 4], v.x, v.y, v.z, v.w);
      }
      for (int idx = tid; idx < 32 * 96; idx += 512) {
        int m = idx / 96, j = idx - m * 96, u = j / 3, i = j - u * 3;
        s_xv[i * 2304 + m * 72 + u] = f2b(P.ef[(size_t)(e0 + m) * 160 + 64 + j]);
      }
      for (int idx = tid; idx < 32 * 32; idx += 512) {
        int m = idx >> 5, u = idx & 31;
        const float* v3 = P.ef + (size_t)(e0 + m) * 160 + 64 + u * 3;
        const float* yv = P.env + (size_t)(e0 + m) * 4 + 1;
        s_dot[m * 72 + u] = f2b((v3[0]*yv[0] + v3[1]*yv[1] + v3[2]*yv[2]) * RSQ3);
      }
      __syncthreads();
    }
  }

  // ---------------- final store ----------------
  const size_t orow = (size_t)(e0 + mrow) * 160;
  {
    int n0 = nq * 16;
    float4 o;
    o.x = oacc_s[0]*RS64; o.y = oacc_s[1]*RS64;
    o.z = oacc_s[2]*RS64; o.w = oacc_s[3]*RS64;
    *(float4*)(P.out + orow + n0 + g * 4) = o;
  }
  {
    int i = nq >> 1, n0 = (nq & 1) * 16;
#pragma unroll
    for (int r = 0; r < 4; ++r)
      P.out[orow + 64 + (size_t)(n0 + g * 4 + r) * 3 + i] = oacc_v0[r] * RS32;
  }
  if (nq < 2) {
    int n0 = (nq & 1) * 16;
#pragma unroll
    for (int r = 0; r < 4; ++r)
      P.out[orow + 64 + (size_t)(n0 + g * 4 + r) * 3 + 2] = oacc_v1[r] * RS32;
  }
}

extern "C" void kernel_launch(void* const* d_in, const int* in_sizes, int n_in,
                              void* d_out, int out_size, void* d_ws, size_t ws_size,
                              hipStream_t stream) {
  PrepArgs A;
  const int src_idx[22] = {21,22,23, 24,25,26, 5,7,6,8, 9,11,10,12, 13,14, 15,16, 17,18, 19,20};
  const int Ks[22] = {64,64,64, 64,64,64, 128,128,64,64, 64,64,32,32, 128,64, 128,64, 64,32, 64,32};
  const int Ns[22] = {64,64,192, 64,64,192, 64,32,64,32, 64,32,64,32, 64,32, 64,32, 64,32, 64,32};
  const int Os[22] = {O_nm1,O_nm2,O_nm3, O_em1,O_em2,O_em3,
                      O_nss,O_nsv,O_nvv,O_nvs, O_ess,O_esv,O_evv,O_evs,
                      O_nss2,O_nsv2, O_ess2,O_esv2, O_nos,O_nov, O_eos,O_eov};
  for (int i = 0; i < 22; ++i) {
    A.src[i] = (const float*)d_in[src_idx[i]];
    A.K[i] = Ks[i]; A.N[i] = Ns[i]; A.ofs[i] = Os[i];
  }
  A.dst = (ushort*)d_ws;
  prep_kernel<<<dim3(22), dim3(256), 0, stream>>>(A);

  Ptrs P;
  P.src  = (const float*)d_in[0];
  P.dst  = (const float*)d_in[1];
  P.ef   = (const float*)d_in[2];
  P.env  = (const float*)d_in[3];
  P.scal = (const float*)d_in[4];
  P.wf   = (const ushort*)d_ws;
  P.out  = (float*)d_out;

  const int E = in_sizes[0] / 160;  // 131072
  mp_kernel<<<dim3(E / 32), dim3(512), 0, stream>>>(P);
}

// Round 6
// 181.310 us; speedup vs baseline: 100.2840x; 1.7437x over previous
//
#include <hip/hip_runtime.h>

// R6: barrier-free wave-private pipeline. Each wave owns 16 edges end-to-end.
// lane(c,g): c=edge (0..15), g=quad (0..3). D-tiles lane-local; stage-to-stage
// repack via wave-private LDS slice (b64 write / b128 read, same-wave => no
// __syncthreads anywhere). Weights pre-packed to MFMA A-fragment layout in ws.

typedef short  bf16x8 __attribute__((ext_vector_type(8)));
typedef float  f32x4  __attribute__((ext_vector_type(4)));

constexpr float BETA  = 1.6791767f;
constexpr float RS128 = 0.088388347648318447f;
constexpr float RS64  = 0.125f;
constexpr float RS32  = 0.176776695296636881f;
constexpr float RSQ3  = 0.577350269189625842f;

enum : int {
  O_nm1 = 0,      O_nm2 = 4096,   O_nm3 = 8192,
  O_em1 = 20480,  O_em2 = 24576,  O_em3 = 28672,
  O_nss = 40960,  O_nsv = 49152,  O_nvv = 53248,  O_nvs = 57344,
  O_ess = 59392,  O_esv = 63488,  O_evv = 65536,  O_evs = 67584,
  O_nss2= 68608,  O_nsv2= 76800,  O_ess2= 78848,  O_esv2= 87040,
  O_nos = 89088,  O_nov = 93184,  O_eos = 94208,  O_eov = 98304,
  W_TOTAL = 99328
};

struct Ptrs {
  const float *src, *dst, *ef, *env, *scal;
  const ushort* wf;
  float *out;
};

struct PrepArgs {
  const float* src[22];
  int K[22], N[22], ofs[22];
  ushort* dst;
};

__device__ __forceinline__ ushort f2b(float x) {
  union { float f; unsigned u; } v; v.f = x;
  unsigned r = v.u + 0x7fffu + ((v.u >> 16) & 1u);
  return (ushort)(r >> 16);
}
__device__ __forceinline__ unsigned pk2(float a, float b) {
  unsigned r;
  asm("v_cvt_pk_bf16_f32 %0, %1, %2" : "=v"(r) : "v"(a), "v"(b));
  return r;
}
__device__ __forceinline__ float plo(unsigned p) {
  union { unsigned u; float f; } v; v.u = p << 16; return v.f;
}
__device__ __forceinline__ float phi(unsigned p) {
  union { unsigned u; float f; } v; v.u = p & 0xffff0000u; return v.f;
}

// ---------------- prep: pack W^T into fragment-major bf16 ----------------
__global__ __launch_bounds__(256) void prep_kernel(PrepArgs A) {
  const int mat = blockIdx.x;
  const float* __restrict__ src = A.src[mat];
  const int K = A.K[mat], N = A.N[mat], KS = K >> 5;
  ushort* dst = A.dst + A.ofs[mat];
  const int total = (N * K) >> 3;
  for (int gi = threadIdx.x; gi < total; gi += 256) {
    int t = gi / (64 * KS), r = gi - t * 64 * KS;
    int ks = r >> 6, lane = r & 63;
    int cc = lane & 15, gg = lane >> 4;
    int n = t * 16 + cc, k0 = ks * 32 + gg * 8;
    ushort v[8];
#pragma unroll
    for (int j = 0; j < 8; ++j) v[j] = f2b(src[(size_t)(k0 + j) * N + n]);
    *(uint4*)(dst + (size_t)gi * 8) = *(const uint4*)v;
  }
}

// GEMM tiles: A from packed global weights, B frags given; D tiles out.
template<int T, int KS>
__device__ __forceinline__ void gtiles(const ushort* __restrict__ wb, unsigned lofs,
                                       const bf16x8* bf, f32x4* out) {
#pragma unroll
  for (int t = 0; t < T; ++t) {
    f32x4 acc = (f32x4){0, 0, 0, 0};
#pragma unroll
    for (int ks = 0; ks < KS; ++ks) {
      bf16x8 a = *(const bf16x8*)(wb + (t * KS + ks) * 512 + lofs);
      acc = __builtin_amdgcn_mfma_f32_16x16x32_bf16(a, bf[ks], acc, 0, 0, 0);
    }
    out[t] = acc;
  }
}

__device__ __forceinline__ void put2(ushort* b, int cg, int col, const f32x4& d) {
  uint2 p; p.x = pk2(d[0], d[1]); p.y = pk2(d[2], d[3]);
  *(uint2*)(b + cg + col) = p;
}
__device__ __forceinline__ bf16x8 getf(const ushort* b, int cg, int col, int g) {
  return *(const bf16x8*)(b + cg + col + 8 * g);
}
__device__ __forceinline__ bf16x8 ldf8(const float* __restrict__ p) {
  float4 a = *(const float4*)p, b4 = *(const float4*)(p + 4);
  union { unsigned u[4]; bf16x8 v; } r;
  r.u[0] = pk2(a.x, a.y); r.u[1] = pk2(a.z, a.w);
  r.u[2] = pk2(b4.x, b4.y); r.u[3] = pk2(b4.z, b4.w);
  return r.v;
}
// load 24 f32 (8 vectors x 3 comps), emit dot frag + 3 xv frags
__device__ __forceinline__ void vecwin(const float* __restrict__ p,
                                       float y0, float y1, float y2,
                                       bf16x8& dotf, bf16x8* xvf) {
  float v[24];
#pragma unroll
  for (int q = 0; q < 6; ++q) *(float4*)&v[4 * q] = *(const float4*)(p + 4 * q);
  float dj[8];
#pragma unroll
  for (int j = 0; j < 8; ++j)
    dj[j] = (v[3 * j] * y0 + v[3 * j + 1] * y1 + v[3 * j + 2] * y2) * RSQ3;
  union { unsigned u[4]; bf16x8 w; } t;
#pragma unroll
  for (int q = 0; q < 4; ++q) t.u[q] = pk2(dj[2 * q], dj[2 * q + 1]);
  dotf = t.w;
#pragma unroll
  for (int i = 0; i < 3; ++i) {
#pragma unroll
    for (int q = 0; q < 4; ++q) t.u[q] = pk2(v[6 * q + i], v[6 * q + 3 + i]);
    xvf[i] = t.w;
  }
}

template<bool ED>
__device__ __forceinline__ void run_path(
    const ushort* __restrict__ WF,
    ushort* b0, ushort* b1, ushort* b2, int cg, int g, unsigned lofs,
    const float* __restrict__ ra, const float* __restrict__ rb,
    const bf16x8* sc, float ys, float yv0, float yv1, float yv2,
    f32x4* os, f32x4 (*ov)[2]) {

  constexpr int KA = ED ? 2 : 4;   // xs K-tiles
  constexpr int KB = ED ? 1 : 2;   // dot/xv K-tiles
  const float SA = ED ? RS64 : RS128;
  const float SB = ED ? RS32 : RS64;
  const ushort* w_m1 = WF + (ED ? O_em1 : O_nm1);
  const ushort* w_m2 = WF + (ED ? O_em2 : O_nm2);
  const ushort* w_m3 = WF + (ED ? O_em3 : O_nm3);
  const ushort* w_ss = WF + (ED ? O_ess : O_nss);
  const ushort* w_sv = WF + (ED ? O_esv : O_nsv);
  const ushort* w_vv = WF + (ED ? O_evv : O_nvv);
  const ushort* w_vs = WF + (ED ? O_evs : O_nvs);
  const ushort* w_s2 = WF + (ED ? O_ess2 : O_nss2);
  const ushort* w_v2 = WF + (ED ? O_esv2 : O_nsv2);
  const ushort* w_os = WF + (ED ? O_eos : O_nos);
  const ushort* w_ov = WF + (ED ? O_eov : O_nov);

  f32x4 d[12];

  // ---- MLP1 -> h0 (b0 cols 0..63) ----
  gtiles<4, 2>(w_m1, lofs, sc, d);
#pragma unroll
  for (int t = 0; t < 4; ++t) {
    f32x4 o;
#pragma unroll
    for (int r = 0; r < 4; ++r) { float z = d[t][r] * 0.125f; o[r] = BETA * z / (1.f + __expf(-z)); }
    put2(b0, cg, 16 * t + 4 * g, o);
  }
  // ---- MLP2 -> h1 (b1 cols 0..63) ----
  {
    bf16x8 hf[2] = { getf(b0, cg, 0, g), getf(b0, cg, 32, g) };
    gtiles<4, 2>(w_m2, lofs, hf, d);
  }
#pragma unroll
  for (int t = 0; t < 4; ++t) {
    f32x4 o;
#pragma unroll
    for (int r = 0; r < 4; ++r) { float z = d[t][r] * 0.125f; o[r] = BETA * z / (1.f + __expf(-z)); }
    put2(b1, cg, 16 * t + 4 * g, o);
  }
  // ---- MLP3 -> w (packed bf16 in regs, D layout) ----
  {
    bf16x8 hf[2] = { getf(b1, cg, 0, g), getf(b1, cg, 32, g) };
    gtiles<12, 2>(w_m3, lofs, hf, d);
  }
  uint2 Wp[12];
#pragma unroll
  for (int t = 0; t < 12; ++t) {
    Wp[t].x = pk2(d[t][0] * 0.125f, d[t][1] * 0.125f);
    Wp[t].y = pk2(d[t][2] * 0.125f, d[t][3] * 0.125f);
  }

  // ---- stage inputs for TP ----
  bf16x8 xsf[4];
  xsf[0] = ldf8(ra + 8 * g);
  xsf[1] = ldf8(ra + 32 + 8 * g);
  if (!ED) {
    xsf[2] = ldf8(rb + 8 * g);
    xsf[3] = ldf8(rb + 32 + 8 * g);
  }
  bf16x8 dotf[2]; bf16x8 xvi[3][2];
  {
    bf16x8 tmp[3];
    vecwin(ra + 64 + 24 * g, yv0, yv1, yv2, dotf[0], tmp);
    xvi[0][0] = tmp[0]; xvi[1][0] = tmp[1]; xvi[2][0] = tmp[2];
    if (!ED) {
      vecwin(rb + 64 + 24 * g, yv0, yv1, yv2, dotf[1], tmp);
      xvi[0][1] = tmp[0]; xvi[1][1] = tmp[1]; xvi[2][1] = tmp[2];
    }
  }

  // ---- TP: m_sp -> b0 cols 0..127 ----
  gtiles<4, KA>(w_ss, lofs, xsf, d);          // s_a
#pragma unroll
  for (int t = 0; t < 4; ++t) {
    f32x4 m;
    m[0] = d[t][0] * ys * SA * plo(Wp[t].x); m[1] = d[t][1] * ys * SA * phi(Wp[t].x);
    m[2] = d[t][2] * ys * SA * plo(Wp[t].y); m[3] = d[t][3] * ys * SA * phi(Wp[t].y);
    put2(b0, cg, 16 * t + 4 * g, m);
  }
  gtiles<4, KB>(w_vv, lofs, dotf, d);         // s_b
#pragma unroll
  for (int t = 0; t < 4; ++t) {
    f32x4 m;
    m[0] = d[t][0] * SB * plo(Wp[4 + t].x); m[1] = d[t][1] * SB * phi(Wp[4 + t].x);
    m[2] = d[t][2] * SB * plo(Wp[4 + t].y); m[3] = d[t][3] * SB * phi(Wp[4 + t].y);
    put2(b0, cg, 64 + 16 * t + 4 * g, m);
  }
  // v_a shared tiles
  f32x4 ga[2];
  gtiles<2, KA>(w_sv, lofs, xsf, ga);
  // v_b per i -> m_v[i]: i0 -> b1 cols 0..63, i1 -> b1 cols 64..127, i2 -> b2 cols 0..63
#pragma unroll
  for (int i = 0; i < 3; ++i) {
    f32x4 db[2];
    gtiles<2, KB>(w_vs, lofs, xvi[i], db);
    float yvi = (i == 0) ? yv0 : ((i == 1) ? yv1 : yv2);
    ushort* mb = (i == 2) ? b2 : b1;
    int mbase = (i == 1) ? 64 : 0;
#pragma unroll
    for (int t = 0; t < 2; ++t) {             // v_a part: n = 16t+..
      f32x4 m;
      m[0] = ga[t][0] * SA * yvi * plo(Wp[8 + t].x); m[1] = ga[t][1] * SA * yvi * phi(Wp[8 + t].x);
      m[2] = ga[t][2] * SA * yvi * plo(Wp[8 + t].y); m[3] = ga[t][3] * SA * yvi * phi(Wp[8 + t].y);
      put2(mb, cg, mbase + 16 * t + 4 * g, m);
    }
#pragma unroll
    for (int t = 0; t < 2; ++t) {             // v_b part: n = 32+16t+..
      f32x4 m;
      m[0] = db[t][0] * ys * SB * plo(Wp[10 + t].x); m[1] = db[t][1] * ys * SB * phi(Wp[10 + t].x);
      m[2] = db[t][2] * ys * SB * plo(Wp[10 + t].y); m[3] = db[t][3] * ys * SB * phi(Wp[10 + t].y);
      put2(mb, cg, mbase + 32 + 16 * t + 4 * g, m);
    }
  }

  // ---- SL: n_s -> b2 cols 64..127 ; n_v[i] -> b0 cols i*32.. ----
  bf16x8 mpf[4];
#pragma unroll
  for (int ks = 0; ks < 4; ++ks) mpf[ks] = getf(b0, cg, 32 * ks, g);
  bf16x8 mvf[3][2];
#pragma unroll
  for (int ks = 0; ks < 2; ++ks) {
    mvf[0][ks] = getf(b1, cg, 32 * ks, g);
    mvf[1][ks] = getf(b1, cg, 64 + 32 * ks, g);
    mvf[2][ks] = getf(b2, cg, 32 * ks, g);
  }
  gtiles<4, 4>(w_s2, lofs, mpf, d);
#pragma unroll
  for (int t = 0; t < 4; ++t) {
    f32x4 m = { d[t][0] * RS128, d[t][1] * RS128, d[t][2] * RS128, d[t][3] * RS128 };
    put2(b2, cg, 64 + 16 * t + 4 * g, m);
  }
#pragma unroll
  for (int i = 0; i < 3; ++i) {
    f32x4 dn[2];
    gtiles<2, 2>(w_v2, lofs, mvf[i], dn);
#pragma unroll
    for (int t = 0; t < 2; ++t) {
      f32x4 m = { dn[t][0] * RS64, dn[t][1] * RS64, dn[t][2] * RS64, dn[t][3] * RS64 };
      put2(b0, cg, i * 32 + 16 * t + 4 * g, m);
    }
  }

  // ---- OUT: accumulate ----
  {
    bf16x8 nsf[2] = { getf(b2, cg, 64, g), getf(b2, cg, 96, g) };
#pragma unroll
    for (int t = 0; t < 4; ++t) {
#pragma unroll
      for (int ks = 0; ks < 2; ++ks) {
        bf16x8 a = *(const bf16x8*)(w_os + (t * 2 + ks) * 512 + lofs);
        os[t] = __builtin_amdgcn_mfma_f32_16x16x32_bf16(a, nsf[ks], os[t], 0, 0, 0);
      }
    }
#pragma unroll
    for (int i = 0; i < 3; ++i) {
      bf16x8 nvf = getf(b0, cg, i * 32, g);
#pragma unroll
      for (int t = 0; t < 2; ++t) {
        bf16x8 a = *(const bf16x8*)(w_ov + t * 512 + lofs);
        ov[i][t] = __builtin_amdgcn_mfma_f32_16x16x32_bf16(a, nvf, ov[i][t], 0, 0, 0);
      }
    }
  }
}

__global__ void mp_kernel(Ptrs P) {
  const int tid  = threadIdx.x;
  const int lane = tid & 63, wid = tid >> 6;
  const int c    = lane & 15, g  = lane >> 4;
  const unsigned lofs = lane * 8;
  const int cg   = c * 136;
  const int e    = (blockIdx.x * 4 + wid) * 16 + c;

  __shared__ ushort sb[4][3][16][136];
  ushort* b0 = &sb[wid][0][0][0];
  ushort* b1 = &sb[wid][1][0][0];
  ushort* b2 = &sb[wid][2][0][0];

  const float* __restrict__ rs = P.src + (size_t)e * 160;
  const float* __restrict__ rd = P.dst + (size_t)e * 160;
  const float* __restrict__ re = P.ef  + (size_t)e * 160;
  const float* __restrict__ rq = P.scal + (size_t)e * 64;

  float4 ev = *(const float4*)(P.env + (size_t)e * 4);
  const float ys = ev.x, yv0 = ev.y, yv1 = ev.z, yv2 = ev.w;

  bf16x8 sc[2];
  sc[0] = ldf8(rq + 8 * g);
  sc[1] = ldf8(rq + 32 + 8 * g);

  f32x4 os[4]; f32x4 ov[3][2];
#pragma unroll
  for (int t = 0; t < 4; ++t) os[t] = (f32x4){0, 0, 0, 0};
#pragma unroll
  for (int i = 0; i < 3; ++i)
#pragma unroll
    for (int t = 0; t < 2; ++t) ov[i][t] = (f32x4){0, 0, 0, 0};

  run_path<false>(P.wf, b0, b1, b2, cg, g, lofs, rs, rd, sc, ys, yv0, yv1, yv2, os, ov);
  run_path<true >(P.wf, b0, b1, b2, cg, g, lofs, re, re, sc, ys, yv0, yv1, yv2, os, ov);

  // ---- store ----
  float* __restrict__ po = P.out + (size_t)e * 160;
#pragma unroll
  for (int t = 0; t < 4; ++t) {
    float4 o = { os[t][0] * RS64, os[t][1] * RS64, os[t][2] * RS64, os[t][3] * RS64 };
    *(float4*)(po + 16 * t + 4 * g) = o;
  }
#pragma unroll
  for (int t = 0; t < 2; ++t) {
    float vv[12];
#pragma unroll
    for (int r = 0; r < 4; ++r)
#pragma unroll
      for (int i = 0; i < 3; ++i) vv[3 * r + i] = ov[i][t][r] * RS32;
    *(float4*)(po + 64 + 48 * t + 12 * g)     = *(float4*)&vv[0];
    *(float4*)(po + 64 + 48 * t + 12 * g + 4) = *(float4*)&vv[4];
    *(float4*)(po + 64 + 48 * t + 12 * g + 8) = *(float4*)&vv[8];
  }
}

extern "C" void kernel_launch(void* const* d_in, const int* in_sizes, int n_in,
                              void* d_out, int out_size, void* d_ws, size_t ws_size,
                              hipStream_t stream) {
  PrepArgs A;
  const int src_idx[22] = {21,22,23, 24,25,26, 5,7,6,8, 9,11,10,12, 13,14, 15,16, 17,18, 19,20};
  const int Ks[22] = {64,64,64, 64,64,64, 128,128,64,64, 64,64,32,32, 128,64, 128,64, 64,32, 64,32};
  const int Ns[22] = {64,64,192, 64,64,192, 64,32,64,32, 64,32,64,32, 64,32, 64,32, 64,32, 64,32};
  const int Os[22] = {O_nm1,O_nm2,O_nm3, O_em1,O_em2,O_em3,
                      O_nss,O_nsv,O_nvv,O_nvs, O_ess,O_esv,O_evv,O_evs,
                      O_nss2,O_nsv2, O_ess2,O_esv2, O_nos,O_nov, O_eos,O_eov};
  for (int i = 0; i < 22; ++i) {
    A.src[i] = (const float*)d_in[src_idx[i]];
    A.K[i] = Ks[i]; A.N[i] = Ns[i]; A.ofs[i] = Os[i];
  }
  A.dst = (ushort*)d_ws;
  prep_kernel<<<dim3(22), dim3(256), 0, stream>>>(A);

  Ptrs P;
  P.src  = (const float*)d_in[0];
  P.dst  = (const float*)d_in[1];
  P.ef   = (const float*)d_in[2];
  P.env  = (const float*)d_in[3];
  P.scal = (const float*)d_in[4];
  P.wf   = (const ushort*)d_ws;
  P.out  = (float*)d_out;

  const int E = in_sizes[0] / 160;  // 131072
  mp_kernel<<<dim3(E / 64), dim3(256), 0, stream>>>(P);
}

// Round 7
// 134.722 us; speedup vs baseline: 134.9629x; 1.3458x over previous
//
#include <hip/hip_runtime.h>

// R7: R6 wave-private pipeline + VGPR headroom (__launch_bounds__(256,3) ~168 regs)
// + explicit load-then-mfma stages + node/edge MLP interleaving (2x ILP) +
// early-issued TP input loads. Dataflow identical to R6 (verified).

typedef short  bf16x8 __attribute__((ext_vector_type(8)));
typedef float  f32x4  __attribute__((ext_vector_type(4)));

constexpr float BETA  = 1.6791767f;
constexpr float RS128 = 0.088388347648318447f;
constexpr float RS64  = 0.125f;
constexpr float RS32  = 0.176776695296636881f;
constexpr float RSQ3  = 0.577350269189625842f;

enum : int {
  O_nm1 = 0,      O_nm2 = 4096,   O_nm3 = 8192,
  O_em1 = 20480,  O_em2 = 24576,  O_em3 = 28672,
  O_nss = 40960,  O_nsv = 49152,  O_nvv = 53248,  O_nvs = 57344,
  O_ess = 59392,  O_esv = 63488,  O_evv = 65536,  O_evs = 67584,
  O_nss2= 68608,  O_nsv2= 76800,  O_ess2= 78848,  O_esv2= 87040,
  O_nos = 89088,  O_nov = 93184,  O_eos = 94208,  O_eov = 98304,
  W_TOTAL = 99328
};

struct Ptrs {
  const float *src, *dst, *ef, *env, *scal;
  const ushort* wf;
  float *out;
};

struct PrepArgs {
  const float* src[22];
  int K[22], N[22], ofs[22];
  ushort* dst;
};

__device__ __forceinline__ ushort f2b(float x) {
  union { float f; unsigned u; } v; v.f = x;
  unsigned r = v.u + 0x7fffu + ((v.u >> 16) & 1u);
  return (ushort)(r >> 16);
}
__device__ __forceinline__ unsigned pk2(float a, float b) {
  unsigned r;
  asm("v_cvt_pk_bf16_f32 %0, %1, %2" : "=v"(r) : "v"(a), "v"(b));
  return r;
}
__device__ __forceinline__ float plo(unsigned p) {
  union { unsigned u; float f; } v; v.u = p << 16; return v.f;
}
__device__ __forceinline__ float phi(unsigned p) {
  union { unsigned u; float f; } v; v.u = p & 0xffff0000u; return v.f;
}

// ---------------- prep: pack W^T into fragment-major bf16 ----------------
__global__ __launch_bounds__(256) void prep_kernel(PrepArgs A) {
  const int mat = blockIdx.x;
  const float* __restrict__ src = A.src[mat];
  const int K = A.K[mat], N = A.N[mat], KS = K >> 5;
  ushort* dst = A.dst + A.ofs[mat];
  const int total = (N * K) >> 3;
  for (int gi = threadIdx.x; gi < total; gi += 256) {
    int t = gi / (64 * KS), r = gi - t * 64 * KS;
    int ks = r >> 6, lane = r & 63;
    int cc = lane & 15, gg = lane >> 4;
    int n = t * 16 + cc, k0 = ks * 32 + gg * 8;
    ushort v[8];
#pragma unroll
    for (int j = 0; j < 8; ++j) v[j] = f2b(src[(size_t)(k0 + j) * N + n]);
    *(uint4*)(dst + (size_t)gi * 8) = *(const uint4*)v;
  }
}

template<int N>
__device__ __forceinline__ void lda(const ushort* __restrict__ wb, unsigned lofs, bf16x8* a) {
#pragma unroll
  for (int i = 0; i < N; ++i) a[i] = *(const bf16x8*)(wb + i * 512 + lofs);
}
template<int T, int KS>
__device__ __forceinline__ void mfm(const bf16x8* a, const bf16x8* bf, f32x4* out) {
#pragma unroll
  for (int t = 0; t < T; ++t) {
    f32x4 acc = (f32x4){0, 0, 0, 0};
#pragma unroll
    for (int ks = 0; ks < KS; ++ks)
      acc = __builtin_amdgcn_mfma_f32_16x16x32_bf16(a[t * KS + ks], bf[ks], acc, 0, 0, 0);
    out[t] = acc;
  }
}
template<int T, int KS>
__device__ __forceinline__ void mfmacc(const bf16x8* a, const bf16x8* bf, f32x4* out) {
#pragma unroll
  for (int t = 0; t < T; ++t)
#pragma unroll
    for (int ks = 0; ks < KS; ++ks)
      out[t] = __builtin_amdgcn_mfma_f32_16x16x32_bf16(a[t * KS + ks], bf[ks], out[t], 0, 0, 0);
}

__device__ __forceinline__ void put2(ushort* b, int cg, int col, const f32x4& d) {
  uint2 p; p.x = pk2(d[0], d[1]); p.y = pk2(d[2], d[3]);
  *(uint2*)(b + cg + col) = p;
}
__device__ __forceinline__ bf16x8 getf(const ushort* b, int cg, int col, int g) {
  return *(const bf16x8*)(b + cg + col + 8 * g);
}
__device__ __forceinline__ bf16x8 ldf8(const float* __restrict__ p) {
  float4 a = *(const float4*)p, b4 = *(const float4*)(p + 4);
  union { unsigned u[4]; bf16x8 v; } r;
  r.u[0] = pk2(a.x, a.y); r.u[1] = pk2(a.z, a.w);
  r.u[2] = pk2(b4.x, b4.y); r.u[3] = pk2(b4.z, b4.w);
  return r.v;
}
__device__ __forceinline__ f32x4 silu4(const f32x4& d) {
  f32x4 o;
#pragma unroll
  for (int r = 0; r < 4; ++r) { float z = d[r] * 0.125f; o[r] = BETA * z / (1.f + __expf(-z)); }
  return o;
}
// load 24 f32 (8 vectors x 3 comps), emit dot frag + 3 xv frags
__device__ __forceinline__ void vecwin(const float* __restrict__ p,
                                       float y0, float y1, float y2,
                                       bf16x8& dotf, bf16x8* xvf) {
  float v[24];
#pragma unroll
  for (int q = 0; q < 6; ++q) *(float4*)&v[4 * q] = *(const float4*)(p + 4 * q);
  float dj[8];
#pragma unroll
  for (int j = 0; j < 8; ++j)
    dj[j] = (v[3 * j] * y0 + v[3 * j + 1] * y1 + v[3 * j + 2] * y2) * RSQ3;
  union { unsigned u[4]; bf16x8 w; } t;
#pragma unroll
  for (int q = 0; q < 4; ++q) t.u[q] = pk2(dj[2 * q], dj[2 * q + 1]);
  dotf = t.w;
#pragma unroll
  for (int i = 0; i < 3; ++i) {
#pragma unroll
    for (int q = 0; q < 4; ++q) t.u[q] = pk2(v[6 * q + i], v[6 * q + 3 + i]);
    xvf[i] = t.w;
  }
}

// ---- TP stage: m_sp -> b0[0..127], m_v -> b1[0..127]/b2[0..63] ----
template<bool ED>
__device__ __forceinline__ void tp_stage(
    const ushort* __restrict__ WF, ushort* b0, ushort* b1, ushort* b2,
    int cg, int g, unsigned lofs,
    const bf16x8* xsf, const bf16x8* dotf, const bf16x8* xvi,   // xvi[i*KB+ks]
    const uint2* Wp, float ys, float yv0, float yv1, float yv2) {
  constexpr int KA = ED ? 2 : 4;
  constexpr int KB = ED ? 1 : 2;
  const float SA = ED ? RS64 : RS128;
  const float SB = ED ? RS32 : RS64;
  const ushort* w_ss = WF + (ED ? O_ess : O_nss);
  const ushort* w_sv = WF + (ED ? O_esv : O_nsv);
  const ushort* w_vv = WF + (ED ? O_evv : O_nvv);
  const ushort* w_vs = WF + (ED ? O_evs : O_nvs);

  {
    bf16x8 a[4 * KA]; f32x4 d[4];
    lda<4 * KA>(w_ss, lofs, a); mfm<4, KA>(a, xsf, d);
#pragma unroll
    for (int t = 0; t < 4; ++t) {
      f32x4 m;
      m[0] = d[t][0] * ys * SA * plo(Wp[t].x); m[1] = d[t][1] * ys * SA * phi(Wp[t].x);
      m[2] = d[t][2] * ys * SA * plo(Wp[t].y); m[3] = d[t][3] * ys * SA * phi(Wp[t].y);
      put2(b0, cg, 16 * t + 4 * g, m);
    }
  }
  {
    bf16x8 a[4 * KB]; f32x4 d[4];
    lda<4 * KB>(w_vv, lofs, a); mfm<4, KB>(a, dotf, d);
#pragma unroll
    for (int t = 0; t < 4; ++t) {
      f32x4 m;
      m[0] = d[t][0] * SB * plo(Wp[4 + t].x); m[1] = d[t][1] * SB * phi(Wp[4 + t].x);
      m[2] = d[t][2] * SB * plo(Wp[4 + t].y); m[3] = d[t][3] * SB * phi(Wp[4 + t].y);
      put2(b0, cg, 64 + 16 * t + 4 * g, m);
    }
  }
  f32x4 ga[2];
  { bf16x8 a[2 * KA]; lda<2 * KA>(w_sv, lofs, a); mfm<2, KA>(a, xsf, ga); }
  bf16x8 avs[2 * KB];
  lda<2 * KB>(w_vs, lofs, avs);
#pragma unroll
  for (int i = 0; i < 3; ++i) {
    f32x4 db[2];
    mfm<2, KB>(avs, xvi + i * KB, db);
    float yvi = (i == 0) ? yv0 : ((i == 1) ? yv1 : yv2);
    ushort* mb = (i == 2) ? b2 : b1;
    int mbase = (i == 1) ? 64 : 0;
#pragma unroll
    for (int t = 0; t < 2; ++t) {
      f32x4 m;
      m[0] = ga[t][0] * SA * yvi * plo(Wp[8 + t].x); m[1] = ga[t][1] * SA * yvi * phi(Wp[8 + t].x);
      m[2] = ga[t][2] * SA * yvi * plo(Wp[8 + t].y); m[3] = ga[t][3] * SA * yvi * phi(Wp[8 + t].y);
      put2(mb, cg, mbase + 16 * t + 4 * g, m);
    }
#pragma unroll
    for (int t = 0; t < 2; ++t) {
      f32x4 m;
      m[0] = db[t][0] * ys * SB * plo(Wp[10 + t].x); m[1] = db[t][1] * ys * SB * phi(Wp[10 + t].x);
      m[2] = db[t][2] * ys * SB * plo(Wp[10 + t].y); m[3] = db[t][3] * ys * SB * phi(Wp[10 + t].y);
      put2(mb, cg, mbase + 32 + 16 * t + 4 * g, m);
    }
  }
}

// ---- SL + OUT: ns -> b2[64..127], nv -> b0[0..95]; accumulate os/ov ----
template<bool ED>
__device__ __forceinline__ void sl_out_stage(
    const ushort* __restrict__ WF, ushort* b0, ushort* b1, ushort* b2,
    int cg, int g, unsigned lofs, f32x4* os, f32x4 (*ov)[2]) {
  const ushort* w_s2 = WF + (ED ? O_ess2 : O_nss2);
  const ushort* w_v2 = WF + (ED ? O_esv2 : O_nsv2);
  const ushort* w_os = WF + (ED ? O_eos : O_nos);
  const ushort* w_ov = WF + (ED ? O_eov : O_nov);

  bf16x8 mpf[4];
#pragma unroll
  for (int ks = 0; ks < 4; ++ks) mpf[ks] = getf(b0, cg, 32 * ks, g);
  bf16x8 mvf[6];
  mvf[0] = getf(b1, cg, 0, g);  mvf[1] = getf(b1, cg, 32, g);
  mvf[2] = getf(b1, cg, 64, g); mvf[3] = getf(b1, cg, 96, g);
  mvf[4] = getf(b2, cg, 0, g);  mvf[5] = getf(b2, cg, 32, g);
  {
    bf16x8 a[16]; f32x4 d[4];
    lda<16>(w_s2, lofs, a); mfm<4, 4>(a, mpf, d);
#pragma unroll
    for (int t = 0; t < 4; ++t) {
      f32x4 m = { d[t][0] * RS128, d[t][1] * RS128, d[t][2] * RS128, d[t][3] * RS128 };
      put2(b2, cg, 64 + 16 * t + 4 * g, m);
    }
  }
  {
    bf16x8 a[4];
    lda<4>(w_v2, lofs, a);
#pragma unroll
    for (int i = 0; i < 3; ++i) {
      f32x4 dn[2]; mfm<2, 2>(a, mvf + 2 * i, dn);
#pragma unroll
      for (int t = 0; t < 2; ++t) {
        f32x4 m = { dn[t][0] * RS64, dn[t][1] * RS64, dn[t][2] * RS64, dn[t][3] * RS64 };
        put2(b0, cg, i * 32 + 16 * t + 4 * g, m);
      }
    }
  }
  {
    bf16x8 nsf[2] = { getf(b2, cg, 64, g), getf(b2, cg, 96, g) };
    bf16x8 a[8]; lda<8>(w_os, lofs, a);
    mfmacc<4, 2>(a, nsf, os);
  }
  {
    bf16x8 a[2]; lda<2>(w_ov, lofs, a);
#pragma unroll
    for (int i = 0; i < 3; ++i) {
      bf16x8 nvf = getf(b0, cg, i * 32, g);
#pragma unroll
      for (int t = 0; t < 2; ++t)
        ov[i][t] = __builtin_amdgcn_mfma_f32_16x16x32_bf16(a[t], nvf, ov[i][t], 0, 0, 0);
    }
  }
}

__global__ __launch_bounds__(256, 3) void mp_kernel(Ptrs P) {
  const int tid  = threadIdx.x;
  const int lane = tid & 63, wid = tid >> 6;
  const int c    = lane & 15, g  = lane >> 4;
  const unsigned lofs = lane * 8;
  const int cg   = c * 136;
  const int e    = (blockIdx.x * 4 + wid) * 16 + c;
  const ushort* __restrict__ WF = P.wf;

  __shared__ ushort sb[4][3][16][136];
  ushort* b0 = &sb[wid][0][0][0];
  ushort* b1 = &sb[wid][1][0][0];
  ushort* b2 = &sb[wid][2][0][0];

  const float* __restrict__ rs = P.src + (size_t)e * 160;
  const float* __restrict__ rd = P.dst + (size_t)e * 160;
  const float* __restrict__ re = P.ef  + (size_t)e * 160;
  const float* __restrict__ rq = P.scal + (size_t)e * 64;

  float4 ev = *(const float4*)(P.env + (size_t)e * 4);
  const float ys = ev.x, yv0 = ev.y, yv1 = ev.z, yv2 = ev.w;

  bf16x8 sc[2];
  sc[0] = ldf8(rq + 8 * g);
  sc[1] = ldf8(rq + 32 + 8 * g);

  // ---- node TP inputs issued early (independent of MLP chain) ----
  bf16x8 xsf_n[4];
  xsf_n[0] = ldf8(rs + 8 * g);  xsf_n[1] = ldf8(rs + 32 + 8 * g);
  xsf_n[2] = ldf8(rd + 8 * g);  xsf_n[3] = ldf8(rd + 32 + 8 * g);
  bf16x8 dot_n[2]; bf16x8 xv_n[6];   // xv_n[i*2+ks]
  {
    bf16x8 tmp[3];
    vecwin(rs + 64 + 24 * g, yv0, yv1, yv2, dot_n[0], tmp);
    xv_n[0] = tmp[0]; xv_n[2] = tmp[1]; xv_n[4] = tmp[2];
    vecwin(rd + 64 + 24 * g, yv0, yv1, yv2, dot_n[1], tmp);
    xv_n[1] = tmp[0]; xv_n[3] = tmp[1]; xv_n[5] = tmp[2];
  }

  // ---- MLPs: node & edge interleaved (independent chains) ----
  uint2 Wpn[12], Wpe[12];
  {
    bf16x8 an[8], ae[8]; f32x4 dn[4], de[4];
    lda<8>(WF + O_nm1, lofs, an); lda<8>(WF + O_em1, lofs, ae);
    mfm<4, 2>(an, sc, dn); mfm<4, 2>(ae, sc, de);
#pragma unroll
    for (int t = 0; t < 4; ++t) put2(b0, cg, 16 * t + 4 * g, silu4(dn[t]));
#pragma unroll
    for (int t = 0; t < 4; ++t) put2(b2, cg, 16 * t + 4 * g, silu4(de[t]));
    lda<8>(WF + O_nm2, lofs, an); lda<8>(WF + O_em2, lofs, ae);
    bf16x8 hn[2] = { getf(b0, cg, 0, g), getf(b0, cg, 32, g) };
    bf16x8 he[2] = { getf(b2, cg, 0, g), getf(b2, cg, 32, g) };
    mfm<4, 2>(an, hn, dn); mfm<4, 2>(ae, he, de);
#pragma unroll
    for (int t = 0; t < 4; ++t) put2(b1, cg, 16 * t + 4 * g, silu4(dn[t]));
#pragma unroll
    for (int t = 0; t < 4; ++t) put2(b2, cg, 64 + 16 * t + 4 * g, silu4(de[t]));
    bf16x8 h2n[2] = { getf(b1, cg, 0, g), getf(b1, cg, 32, g) };
    bf16x8 h2e[2] = { getf(b2, cg, 64, g), getf(b2, cg, 96, g) };
    {
      bf16x8 a3[24]; f32x4 dw[12];
      lda<24>(WF + O_nm3, lofs, a3); mfm<12, 2>(a3, h2n, dw);
#pragma unroll
      for (int t = 0; t < 12; ++t) {
        Wpn[t].x = pk2(dw[t][0] * 0.125f, dw[t][1] * 0.125f);
        Wpn[t].y = pk2(dw[t][2] * 0.125f, dw[t][3] * 0.125f);
      }
      lda<24>(WF + O_em3, lofs, a3); mfm<12, 2>(a3, h2e, dw);
#pragma unroll
      for (int t = 0; t < 12; ++t) {
        Wpe[t].x = pk2(dw[t][0] * 0.125f, dw[t][1] * 0.125f);
        Wpe[t].y = pk2(dw[t][2] * 0.125f, dw[t][3] * 0.125f);
      }
    }
  }

  f32x4 os[4]; f32x4 ov[3][2];
#pragma unroll
  for (int t = 0; t < 4; ++t) os[t] = (f32x4){0, 0, 0, 0};
#pragma unroll
  for (int i = 0; i < 3; ++i)
#pragma unroll
    for (int t = 0; t < 2; ++t) ov[i][t] = (f32x4){0, 0, 0, 0};

  // ---- node TP ----
  tp_stage<false>(WF, b0, b1, b2, cg, g, lofs, xsf_n, dot_n, xv_n, Wpn, ys, yv0, yv1, yv2);

  // ---- edge TP inputs issued one stage early ----
  bf16x8 xsf_e[2] = { ldf8(re + 8 * g), ldf8(re + 32 + 8 * g) };
  bf16x8 dot_e[1]; bf16x8 xv_e[3];
  {
    bf16x8 tmp[3];
    vecwin(re + 64 + 24 * g, yv0, yv1, yv2, dot_e[0], tmp);
    xv_e[0] = tmp[0]; xv_e[1] = tmp[1]; xv_e[2] = tmp[2];
  }

  // ---- node SL + OUT ----
  sl_out_stage<false>(WF, b0, b1, b2, cg, g, lofs, os, ov);

  // ---- edge TP, SL + OUT ----
  tp_stage<true>(WF, b0, b1, b2, cg, g, lofs, xsf_e, dot_e, xv_e, Wpe, ys, yv0, yv1, yv2);
  sl_out_stage<true>(WF, b0, b1, b2, cg, g, lofs, os, ov);

  // ---- store ----
  float* __restrict__ po = P.out + (size_t)e * 160;
#pragma unroll
  for (int t = 0; t < 4; ++t) {
    float4 o = { os[t][0] * RS64, os[t][1] * RS64, os[t][2] * RS64, os[t][3] * RS64 };
    *(float4*)(po + 16 * t + 4 * g) = o;
  }
#pragma unroll
  for (int t = 0; t < 2; ++t) {
    float vv[12];
#pragma unroll
    for (int r = 0; r < 4; ++r)
#pragma unroll
      for (int i = 0; i < 3; ++i) vv[3 * r + i] = ov[i][t][r] * RS32;
    *(float4*)(po + 64 + 48 * t + 12 * g)     = *(float4*)&vv[0];
    *(float4*)(po + 64 + 48 * t + 12 * g + 4) = *(float4*)&vv[4];
    *(float4*)(po + 64 + 48 * t + 12 * g + 8) = *(float4*)&vv[8];
  }
}

extern "C" void kernel_launch(void* const* d_in, const int* in_sizes, int n_in,
                              void* d_out, int out_size, void* d_ws, size_t ws_size,
                              hipStream_t stream) {
  PrepArgs A;
  const int src_idx[22] = {21,22,23, 24,25,26, 5,7,6,8, 9,11,10,12, 13,14, 15,16, 17,18, 19,20};
  const int Ks[22] = {64,64,64, 64,64,64, 128,128,64,64, 64,64,32,32, 128,64, 128,64, 64,32, 64,32};
  const int Ns[22] = {64,64,192, 64,64,192, 64,32,64,32, 64,32,64,32, 64,32, 64,32, 64,32, 64,32};
  const int Os[22] = {O_nm1,O_nm2,O_nm3, O_em1,O_em2,O_em3,
                      O_nss,O_nsv,O_nvv,O_nvs, O_ess,O_esv,O_evv,O_evs,
                      O_nss2,O_nsv2, O_ess2,O_esv2, O_nos,O_nov, O_eos,O_eov};
  for (int i = 0; i < 22; ++i) {
    A.src[i] = (const float*)d_in[src_idx[i]];
    A.K[i] = Ks[i]; A.N[i] = Ns[i]; A.ofs[i] = Os[i];
  }
  A.dst = (ushort*)d_ws;
  prep_kernel<<<dim3(22), dim3(256), 0, stream>>>(A);

  Ptrs P;
  P.src  = (const float*)d_in[0];
  P.dst  = (const float*)d_in[1];
  P.ef   = (const float*)d_in[2];
  P.env  = (const float*)d_in[3];
  P.scal = (const float*)d_in[4];
  P.wf   = (const ushort*)d_ws;
  P.out  = (float*)d_out;

  const int E = in_sizes[0] / 160;  // 131072
  mp_kernel<<<dim3(E / 64), dim3(256), 0, stream>>>(P);
}